// Round 24
// baseline (369.723 us; speedup 1.0000x reference)
//
#include <hip/hip_runtime.h>
#include <hip/hip_bf16.h>

typedef unsigned int u32;
typedef unsigned long long u64;
typedef short bf16x8 __attribute__((ext_vector_type(8)));
typedef float f32x4 __attribute__((ext_vector_type(4)));

#define NCAND 1000
#define NANCH 25200

__device__ __forceinline__ float sig_acc(float x) { return 1.0f / (1.0f + expf(-x)); }
__device__ __forceinline__ float silu_fast(float v) { return v / (1.0f + __expf(-v)); }
__device__ __forceinline__ unsigned short f2b(float f) {
    __hip_bfloat16 h = __float2bfloat16(f);
    return *reinterpret_cast<unsigned short*>(&h);
}
__device__ __forceinline__ float b2f(unsigned short u) {
    return __uint_as_float(((u32)u) << 16);
}
__device__ __forceinline__ int swz(int p) { return (p & 3) ^ ((p >> 2) & 3); }

// async global->LDS, 16B per lane; dst = wave-uniform base + lane*16
__device__ __forceinline__ void gload16(const void* g, void* l) {
    __builtin_amdgcn_global_load_lds((const __attribute__((address_space(1))) void*)g,
                                     (__attribute__((address_space(3))) void*)l, 16, 0, 0);
}

// ---------------------------------------------------------------------------
// Merged prep (R20): wdt transposes + zerobuf + wprep + NCHW->NHWC in 1 launch
// ---------------------------------------------------------------------------
__global__ __launch_bounds__(256) void prep_all_kernel(
    const float* __restrict__ w_det0, const float* __restrict__ w_det1, const float* __restrict__ w_det2,
    float* __restrict__ wdt0, float* __restrict__ wdt1, float* __restrict__ wdt2,
    const float* __restrict__ w_seg0, const float* __restrict__ w_seg1,
    const float* __restrict__ w_seg2, const float* __restrict__ w_sc,
    unsigned short* __restrict__ wp0, unsigned short* __restrict__ wp1,
    unsigned short* __restrict__ wp2, unsigned short* __restrict__ wp3,
    const float* __restrict__ x0, const float* __restrict__ x1, const float* __restrict__ x2,
    unsigned short* __restrict__ x0n, unsigned short* __restrict__ x1n, unsigned short* __restrict__ x2n,
    float* __restrict__ zerobuf)
{
    __shared__ float tile[64][65];
    int b = blockIdx.x, t = threadIdx.x;
    if (b < 112) {
        const float* w; float* wdt; int C, c0, oc0;
        if (b < 16)      { w = w_det0; wdt = wdt0; C = 256;  c0 = (b & 3) * 64;  oc0 = (b >> 2) * 64; }
        else if (b < 48) { int l = b - 16; w = w_det1; wdt = wdt1; C = 512;  c0 = (l & 7) * 64;  oc0 = (l >> 3) * 64; }
        else             { int l = b - 48; w = w_det2; wdt = wdt2; C = 1024; c0 = (l & 15) * 64; oc0 = (l >> 4) * 64; }
        for (int k = t; k < 1024; k += 256) {
            int oo = k >> 4, q = k & 15;
            int oc = oc0 + oo;
            float4 v = {0.f, 0.f, 0.f, 0.f};
            if (oc < 255) v = *(const float4*)&w[(size_t)oc * C + c0 + q * 4];
            tile[oo][q * 4 + 0] = v.x; tile[oo][q * 4 + 1] = v.y;
            tile[oo][q * 4 + 2] = v.z; tile[oo][q * 4 + 3] = v.w;
        }
        __syncthreads();
        for (int k = t; k < 1024; k += 256) {
            int cc = k >> 4, q = k & 15;
            float4 o;
            o.x = tile[q * 4 + 0][cc]; o.y = tile[q * 4 + 1][cc];
            o.z = tile[q * 4 + 2][cc]; o.w = tile[q * 4 + 3][cc];
            *(float4*)&wdt[(size_t)(c0 + cc) * 256 + oc0 + q * 4] = o;
        }
    } else if (b == 112) {
        zerobuf[t] = 0.0f; zerobuf[t + 256] = 0.0f;
    } else if (b < 2865) {
        int l = b - 113;
        const float* w; unsigned short* dst; int Cin, Cout;
        if (l < 2048)      { w = w_seg0; dst = wp0; Cin = 1024; Cout = 512; }
        else if (l < 2560) { l -= 2048; w = w_seg1; dst = wp1; Cin = 512; Cout = 256; }
        else if (l < 2688) { l -= 2560; w = w_seg2; dst = wp2; Cin = 256; Cout = 128; }
        else               { l -= 2688; w = w_sc;  dst = wp3; Cin = 128; Cout = 128; }
        int i = l * 256 + t;
        if (i < Cout * Cin) {
            int oc = i / Cin, c = i - oc * Cin;
            int nch = Cin >> 5;
            int ocb = oc >> 6, ocl = oc & 63, chn = c >> 5, cl = c & 31;
            const float* src = w + (size_t)i * 9;
            size_t base = (((size_t)(ocb * nch + chn) * 9) * 64 + ocl) * 32 + cl;
            #pragma unroll
            for (int tap = 0; tap < 9; tap++)
                dst[base + (size_t)tap * 2048] = f2b(src[tap]);
        }
    } else {
        int l = b - 2865;
        const float* x; unsigned short* y; int C, HW, n, c0, p0;
        if (l < 800)       { x = x0; y = x0n; C = 256;  HW = 6400; p0 = (l % 100) * 64; c0 = ((l / 100) & 3) * 64; n = l / 400; }
        else if (l < 1200) { l -= 800;  x = x1; y = x1n; C = 512;  HW = 1600; p0 = (l % 25) * 64; c0 = ((l / 25) & 7) * 64; n = l / 200; }
        else               { l -= 1200; x = x2; y = x2n; C = 1024; HW = 400;  p0 = (l % 7) * 64;  c0 = ((l / 7) & 15) * 64; n = l / 112; }
        const float* xb = x + ((size_t)n * C + c0) * HW;
        for (int k = t; k < 1024; k += 256) {
            int cc = k >> 4, q = k & 15;
            int gp = p0 + q * 4;
            float4 v = {0.f, 0.f, 0.f, 0.f};
            if (gp < HW) v = *(const float4*)&xb[(size_t)cc * HW + gp];
            tile[cc][q * 4 + 0] = v.x; tile[cc][q * 4 + 1] = v.y;
            tile[cc][q * 4 + 2] = v.z; tile[cc][q * 4 + 3] = v.w;
        }
        __syncthreads();
        for (int k = t; k < 512; k += 256) {
            int pp = k >> 3, cg = k & 7;
            int gp = p0 + pp;
            if (gp < HW) {
                bf16x8 pk;
                #pragma unroll
                for (int j = 0; j < 8; j++) pk[j] = (short)f2b(tile[cg * 8 + j][pp]);
                *(bf16x8*)&y[((size_t)n * HW + gp) * C + c0 + cg * 8] = pk;
            }
        }
    }
}

// ---------------------------------------------------------------------------
// Det 1x1 conv body (XCD-swizzled), smem passed in. xs 32KB + wsm 8KB = 40KB.
// ---------------------------------------------------------------------------
#define XBUF 21504
__device__ __forceinline__ void det_conv_body(int id, char* smembase,
    const float* __restrict__ x, const float* __restrict__ wdt, const float* __restrict__ bias,
    float* __restrict__ dst, int C, int HW, int c_len, int nsl)
{
    typedef float XS[32][128];
    typedef float WS[32][32];
    XS* xs = (XS*)smembase;
    WS* wsm = (WS*)(smembase + 32768);
    int nx = (HW + 127) >> 7;
    int ngroups = nx * nsl * 2;
    int xcd = id & 7;
    int rest = id >> 3;
    int sub = rest & 7;
    int dgrp = rest >> 3;
    int gidx = dgrp * 8 + xcd;
    if (gidx >= ngroups) return;
    int px = gidx % nx;
    int r0 = gidx / nx;
    int slice = r0 % nsl;
    int b = r0 / nsl;
    int oc0 = sub * 32;
    int px0 = px * 128;
    int c0base = slice * c_len;
    int t = threadIdx.x;
    int lane = t & 63, wv = t >> 6;
    int pxg = t & 31, og = t >> 5;
    int lpx = pxg << 2;
    bool full = (px0 + 128 <= HW);
    const float* xb = x + (size_t)b * C * HW;

    auto stage = [&](int c0, int nb) {
        if (full) {
            for (int i = wv; i < 16; i += 4) {
                const float* src = xb + (size_t)(c0 + 2 * i + (lane >> 5)) * HW + px0 + (lane & 31) * 4;
                gload16(src, &xs[nb][2 * i][0]);
            }
        } else {
            for (int k = t; k < 4096; k += 256) {
                int cc = k >> 7, pp = k & 127;
                int gp = px0 + pp;
                xs[nb][cc][pp] = (gp < HW) ? xb[(size_t)(c0 + cc) * HW + gp] : 0.0f;
            }
        }
        const float* wsrc = wdt + (size_t)(c0 + 8 * wv + (lane >> 3)) * 256 + oc0 + (lane & 7) * 4;
        gload16(wsrc, &wsm[nb][8 * wv][0]);
    };

    float acc[4][4] = {{0.f,0.f,0.f,0.f},{0.f,0.f,0.f,0.f},{0.f,0.f,0.f,0.f},{0.f,0.f,0.f,0.f}};
    int nchk = c_len >> 5;
    stage(c0base, 0);
    __syncthreads();
    int nb = 0;
    for (int ch = 0; ch < nchk; ch++) {
        if (ch + 1 < nchk) stage(c0base + ((ch + 1) << 5), nb ^ 1);
        #pragma unroll 8
        for (int cc = 0; cc < 32; cc++) {
            float4 xv = *(const float4*)&xs[nb][cc][lpx];
            float4 wv4 = *(const float4*)&wsm[nb][cc][og << 2];
            float xr[4] = {xv.x, xv.y, xv.z, xv.w};
            float wr[4] = {wv4.x, wv4.y, wv4.z, wv4.w};
            #pragma unroll
            for (int oo = 0; oo < 4; oo++)
                #pragma unroll
                for (int j = 0; j < 4; j++)
                    acc[oo][j] = fmaf(wr[oo], xr[j], acc[oo][j]);
        }
        __syncthreads();
        nb ^= 1;
    }
    float* outb = dst + (size_t)slice * ((size_t)2 * 255 * HW);
    int gp = px0 + lpx;
    #pragma unroll
    for (int oo = 0; oo < 4; oo++) {
        int oc = oc0 + (og << 2) + oo;
        if (oc >= 255) continue;
        float bv = (nsl == 1) ? bias[oc] : 0.0f;
        float* ob = outb + ((size_t)b * 255 + oc) * HW;
        if (gp + 3 < HW) {
            float4 v; v.x = acc[oo][0]+bv; v.y = acc[oo][1]+bv; v.z = acc[oo][2]+bv; v.w = acc[oo][3]+bv;
            *(float4*)&ob[gp] = v;
        } else {
            for (int j = 0; j < 4; j++) if (gp + j < HW) ob[gp + j] = acc[oo][j] + bv;
        }
    }
}

// ---------------------------------------------------------------------------
// bf16 MFMA 3x3 conv body (R19 XCD-swizzled), guarded-skeleton form.
// dbuf=1: double-buffered (43KB). dbuf=0: single-buffered (21.5KB) — used in
// the merged detseg launch so its static LDS max stays at det's 40KB ->
// 4 blocks/CU (R23 post-mortem: 43KB pushed everyone to 3/CU).
// ---------------------------------------------------------------------------
__device__ __forceinline__ void conv3x3_body(int id, char* smem,
    const unsigned short* __restrict__ in, const unsigned short* __restrict__ wp,
    const float* __restrict__ gain, const float* __restrict__ bias,
    unsigned short* __restrict__ out, const float* __restrict__ zerobuf,
    int Cin, int Cout, int H, int W, int act, int ksl, float* __restrict__ pout,
    int dbuf)
{
    bool on = (threadIdx.x < 256);
    int tilesX = (W + 15) >> 4;
    int tilesY = (H + 15) >> 4;
    int tiles = tilesX * tilesY;
    int nocb = Cout >> 6;
    int ngroups = tiles * ksl * 2;
    int xcd = id & 7;
    int rest = id >> 3;
    int sub = rest % nocb;
    int dgrp = rest / nocb;
    int gidx = dgrp * 8 + xcd;
    if (gidx >= ngroups) return;            // block-uniform
    int tile = gidx % tiles;
    int r0 = gidx / tiles;
    int slice = r0 % ksl;
    int n = r0 / ksl;
    int ocb = sub;
    int tY = tile / tilesX, tX = tile - tY * tilesX;
    int y0 = tY << 4, x0 = tX << 4;
    int oc0 = ocb << 6;
    int t = threadIdx.x;
    int lane = t & 63, wv = t >> 6;
    int lg = lane >> 4, lr = lane & 15;
    int HW = H * W;
    int nch = Cin >> 5;
    int nchunks = nch / ksl;
    int chbase = slice * nchunks;
    const unsigned short* inb = in + (size_t)n * HW * Cin;
    const unsigned short* wpb = wp + (size_t)ocb * ((size_t)nch * 9 * 2048);
    int spix = lane >> 2, sg = lane & 3;

    f32x4 acc[4][4];
    #pragma unroll
    for (int p = 0; p < 4; p++)
        #pragma unroll
        for (int q = 0; q < 4; q++)
            acc[p][q] = (f32x4){0.f, 0.f, 0.f, 0.f};

    auto stageX = [&](int ch, int nbuf) {
        int c0 = ch << 5;
        char* dst0 = smem + nbuf * XBUF;
        for (int i = wv; i < 21; i += 4) {
            int pix = i * 16 + spix;
            int yy = (pix * 57) >> 10;          // pix/18, exact for pix<=335
            int xx = pix - yy * 18;
            int gy = y0 - 1 + yy, gx = x0 - 1 + xx;
            bool oob = (pix >= 324) || (gy < 0) || (gy >= H) || (gx < 0) || (gx >= W);
            int gsw = sg ^ swz(pix);
            const void* src = oob ? (const void*)zerobuf
                : (const void*)(inb + (size_t)(gy * W + gx) * Cin + c0 + gsw * 8);
            gload16(src, dst0 + i * 1024);
        }
    };

    auto compute = [&](const char* sx, int ch) {
        const unsigned short* wsrc = wpb + (size_t)ch * (9 * 2048);
        #pragma unroll 3
        for (int tap = 0; tap < 9; tap++) {
            int dy = tap / 3, dx = tap - dy * 3;
            bf16x8 wf[4];
            #pragma unroll
            for (int q = 0; q < 4; q++)
                wf[q] = *(const bf16x8*)(wsrc + (size_t)(tap * 64 + q * 16 + lr) * 32 + lg * 8);
            #pragma unroll
            for (int p = 0; p < 4; p++) {
                int pix = ((wv << 2) + p + dy) * 18 + dx + lr;
                bf16x8 xf = *(const bf16x8*)(sx + (pix << 6) + ((lg ^ swz(pix)) << 4));
                #pragma unroll
                for (int q = 0; q < 4; q++)
                    acc[p][q] = __builtin_amdgcn_mfma_f32_16x16x32_bf16(wf[q], xf, acc[p][q], 0, 0, 0);
            }
        }
    };

    if (dbuf) {
        if (on) stageX(chbase, 0);
        __syncthreads();
        int nb = 0;
        for (int ci = 0; ci < nchunks; ci++) {
            int ch = chbase + ci;
            if (on && ci + 1 < nchunks) stageX(ch + 1, nb ^ 1);
            if (on) compute(smem + nb * XBUF, ch);
            __syncthreads();
            nb ^= 1;
        }
    } else {
        for (int ci = 0; ci < nchunks; ci++) {
            int ch = chbase + ci;
            if (on) stageX(ch, 0);
            __syncthreads();            // drains gload_lds
            if (on) compute(smem, ch);
            __syncthreads();
        }
    }
    if (!on) return;
    int x = x0 + lr;
    if (x >= W) return;
    if (ksl == 1) {
        #pragma unroll
        for (int p = 0; p < 4; p++) {
            int y = y0 + (wv << 2) + p;
            if (y >= H) continue;
            unsigned short* ob = out + ((size_t)n * HW + (size_t)y * W + x) * Cout + oc0;
            #pragma unroll
            for (int q = 0; q < 4; q++) {
                int obase = (q << 4) + (lg << 2);
                ushort4 pk;
                #pragma unroll
                for (int r2 = 0; r2 < 4; r2++) {
                    int oc = oc0 + obase + r2;
                    float v = acc[p][q][r2] * gain[oc] + bias[oc];
                    if (act) v = silu_fast(v);
                    ((unsigned short*)&pk)[r2] = f2b(v);
                }
                *(ushort4*)&ob[obase] = pk;
            }
        }
    } else {
        float* pb = pout + ((size_t)(slice * 2 + n) * HW) * Cout;
        #pragma unroll
        for (int p = 0; p < 4; p++) {
            int y = y0 + (wv << 2) + p;
            if (y >= H) continue;
            float* ob = pb + ((size_t)y * W + x) * Cout + oc0;
            #pragma unroll
            for (int q = 0; q < 4; q++)
                *(f32x4*)&ob[(q << 4) + (lg << 2)] = acc[p][q];
        }
    }
}

__global__ __launch_bounds__(256) void mfma_conv3x3(
    const unsigned short* __restrict__ in, const unsigned short* __restrict__ wp,
    const float* __restrict__ gain, const float* __restrict__ bias,
    unsigned short* __restrict__ out, const float* __restrict__ zerobuf,
    int Cin, int Cout, int H, int W, int act, int ksl, float* __restrict__ pout)
{
    __shared__ __align__(16) char smem[2 * XBUF];
    conv3x3_body(blockIdx.x, smem, in, wp, gain, bias, out, zerobuf, Cin, Cout, H, W, act, ksl, pout, 1);
}

// ---------------------------------------------------------------------------
// L2: det convs (3 heads) || seg0 conv — LDS capped at 40960 (det's need);
// seg0 runs SINGLE-buffered so the whole launch gets 4 blocks/CU.
// [0,832) det0 | [832,1280) det1 | [1280,1792) det2 | [1792,2048) seg0
// ---------------------------------------------------------------------------
__global__ __launch_bounds__(256) void detseg_conv_kernel(
    const float* __restrict__ xa, const float* __restrict__ wdta, const float* __restrict__ ba, float* __restrict__ da,
    const float* __restrict__ xb2, const float* __restrict__ wdtb, const float* __restrict__ bb, float* __restrict__ db,
    const float* __restrict__ xc, const float* __restrict__ wdtc, const float* __restrict__ bc, float* __restrict__ dc,
    const unsigned short* __restrict__ x2n, const unsigned short* __restrict__ wp0,
    const float* __restrict__ g_seg0, const float* __restrict__ b_seg0,
    unsigned short* __restrict__ f0, const float* __restrict__ zerobuf, float* __restrict__ segp0)
{
    __shared__ __align__(16) char smem[40960];
    int blk = blockIdx.x;
    if (blk < 832)       det_conv_body(blk, smem, xa, wdta, ba, da, 256, 6400, 256, 1);
    else if (blk < 1280) det_conv_body(blk - 832, smem, xb2, wdtb, bb, db, 512, 1600, 256, 2);
    else if (blk < 1792) det_conv_body(blk - 1280, smem, xc, wdtc, bc, dc, 1024, 400, 128, 8);
    else conv3x3_body(blk - 1792, smem, x2n, wp0, g_seg0, b_seg0, f0, zerobuf, 1024, 512, 20, 20, 0, 4, segp0, 0);
}

// ---------------------------------------------------------------------------
// seg split-K combine body
// ---------------------------------------------------------------------------
__device__ __forceinline__ void seg_combine_body(int tid, const float* __restrict__ parts,
    const float* __restrict__ gain, const float* __restrict__ bias,
    unsigned short* __restrict__ out, int nsl, int total4, int C, int act)
{
    if (tid >= total4) return;
    size_t stride = (size_t)total4 * 4;
    float4 s = {0.f, 0.f, 0.f, 0.f};
    for (int sl = 0; sl < nsl; sl++) {
        float4 v = *(const float4*)&parts[sl * stride + (size_t)tid * 4];
        s.x += v.x; s.y += v.y; s.z += v.z; s.w += v.w;
    }
    int oc = (tid * 4) % C;
    float r[4] = {s.x, s.y, s.z, s.w};
    ushort4 pk;
    #pragma unroll
    for (int j = 0; j < 4; j++) {
        float v = r[j] * gain[oc + j] + bias[oc + j];
        if (act) v = silu_fast(v);
        ((unsigned short*)&pk)[j] = f2b(v);
    }
    *(ushort4*)&out[(size_t)tid * 4] = pk;
}

__global__ void seg_combine_kernel(const float* __restrict__ parts,
    const float* __restrict__ gain, const float* __restrict__ bias,
    unsigned short* __restrict__ out, int nsl, int total4, int C, int act)
{
    seg_combine_body(blockIdx.x * 256 + threadIdx.x, parts, gain, bias, out, nsl, total4, C, act);
}

// ---------------------------------------------------------------------------
// L3: det split-K combine (both heads) || seg combine0.
// [0,797) det1 | [797,997) det2 | [997,1397) comb0
// ---------------------------------------------------------------------------
__global__ void combine_both_kernel(
    const float* __restrict__ p1, const float* __restrict__ b1, float* __restrict__ co1,
    const float* __restrict__ p2, const float* __restrict__ b2, float* __restrict__ co2,
    const float* __restrict__ segp0, const float* __restrict__ g_seg0,
    const float* __restrict__ b_seg0, unsigned short* __restrict__ f0)
{
    int b = blockIdx.x, t = threadIdx.x;
    if (b >= 997) {
        seg_combine_body((b - 997) * 256 + t, segp0, g_seg0, b_seg0, f0, 4, 2*400*512/4, 512, 0);
        return;
    }
    const float* parts; const float* bias; float* co; int nsl, HW, tid, total4;
    if (b < 797) { parts = p1; bias = b1; co = co1; nsl = 2; HW = 1600; tid = b * 256 + t; total4 = 2 * 255 * 1600 / 4; }
    else         { parts = p2; bias = b2; co = co2; nsl = 8; HW = 400;  tid = (b - 797) * 256 + t; total4 = 2 * 255 * 400 / 4; }
    if (tid >= total4) return;
    size_t stride = (size_t)2 * 255 * HW;
    float4 s = {0.f, 0.f, 0.f, 0.f};
    for (int sl = 0; sl < nsl; sl++) {
        float4 v = *(const float4*)&parts[sl * stride + (size_t)tid * 4];
        s.x += v.x; s.y += v.y; s.z += v.z; s.w += v.w;
    }
    int oc = ((tid * 4) / HW) % 255;
    float bv = bias[oc];
    s.x += bv; s.y += bv; s.z += bv; s.w += bv;
    *(float4*)&co[(size_t)tid * 4] = s;
}

// ---------------------------------------------------------------------------
// resize body
// ---------------------------------------------------------------------------
__device__ __forceinline__ void resize_add_body(int tid, const unsigned short* __restrict__ f,
    const unsigned short* __restrict__ skip, unsigned short* __restrict__ out,
    int C8, int C, int IH, int IW, int OH, int OW)
{
    int total = 2 * OH * OW * C8;
    if (tid >= total) return;
    int cg = tid % C8; int r = tid / C8;
    int ox = r % OW; r /= OW;
    int oy = r % OH; int n = r / OH;
    float sy = (float)(IH - 1) / (float)(OH - 1);
    float sx = (float)(IW - 1) / (float)(OW - 1);
    float ys = oy * sy, xs = ox * sx;
    int y0 = (int)floorf(ys); if (y0 > IH - 1) y0 = IH - 1;
    int x0 = (int)floorf(xs); if (x0 > IW - 1) x0 = IW - 1;
    int y1 = min(y0 + 1, IH - 1), x1 = min(x0 + 1, IW - 1);
    float fy = ys - (float)y0, fx = xs - (float)x0;
    const unsigned short* fb = f + (size_t)n * IH * IW * C + cg * 8;
    bf16x8 a00 = *(const bf16x8*)&fb[(size_t)(y0 * IW + x0) * C];
    bf16x8 a01 = *(const bf16x8*)&fb[(size_t)(y0 * IW + x1) * C];
    bf16x8 a10 = *(const bf16x8*)&fb[(size_t)(y1 * IW + x0) * C];
    bf16x8 a11 = *(const bf16x8*)&fb[(size_t)(y1 * IW + x1) * C];
    bf16x8 sk = *(const bf16x8*)&skip[(size_t)tid * 8];
    bf16x8 o;
    #pragma unroll
    for (int j = 0; j < 8; j++) {
        float r0 = b2f((unsigned short)a00[j]) * (1.0f - fy) + b2f((unsigned short)a10[j]) * fy;
        float r1 = b2f((unsigned short)a01[j]) * (1.0f - fy) + b2f((unsigned short)a11[j]) * fy;
        float v = r0 * (1.0f - fx) + r1 * fx + b2f((unsigned short)sk[j]);
        o[j] = (short)f2b(v);
    }
    *(bf16x8*)&out[(size_t)tid * 8] = o;
}

// ---------------------------------------------------------------------------
// L4: decode (198 blocks) || resize_add1 (800 blocks)
// ---------------------------------------------------------------------------
__global__ void decode_resize1_kernel(const float* __restrict__ co0, const float* __restrict__ co1,
    const float* __restrict__ co2, float* __restrict__ boxes_all, u64* __restrict__ keys,
    int* __restrict__ cls_all,
    const unsigned short* __restrict__ f0, const unsigned short* __restrict__ x1n,
    unsigned short* __restrict__ r1b)
{
    int blk = blockIdx.x, t = threadIdx.x;
    if (blk >= 198) {
        resize_add_body((blk - 198) * 256 + t, f0, x1n, r1b, 64, 512, 20, 20, 40, 40);
        return;
    }
    const float* conv; int ny, base, total; float stride;
    float aw0, ah0, aw1, ah1, aw2, ah2;
    int tid;
    if (blk < 150) {
        conv = co0; ny = 80; stride = 8.0f; base = 0; total = 38400;
        aw0 = 10.f; ah0 = 13.f; aw1 = 16.f; ah1 = 30.f; aw2 = 33.f; ah2 = 23.f;
        tid = blk * 256 + t;
    } else if (blk < 188) {
        conv = co1; ny = 40; stride = 16.0f; base = 19200; total = 9600;
        aw0 = 30.f; ah0 = 61.f; aw1 = 62.f; ah1 = 45.f; aw2 = 59.f; ah2 = 119.f;
        tid = (blk - 150) * 256 + t;
    } else {
        conv = co2; ny = 20; stride = 32.0f; base = 24000; total = 2400;
        aw0 = 116.f; ah0 = 90.f; aw1 = 156.f; ah1 = 198.f; aw2 = 373.f; ah2 = 326.f;
        tid = (blk - 188) * 256 + t;
    }
    if (tid >= total) return;
    int nx = ny;
    int HW = ny * nx;
    int gx = tid % nx; int r = tid / nx;
    int gy = r % ny; r /= ny;
    int a = r % 3; int b = r / 3;
    const float* cb = conv + ((size_t)b * 255 + a * 85) * HW + (size_t)gy * nx + gx;
    float v0 = cb[0];
    float v1 = cb[(size_t)1 * HW];
    float v2 = cb[(size_t)2 * HW];
    float v3 = cb[(size_t)3 * HW];
    float v4 = cb[(size_t)4 * HW];
    float mx = cb[(size_t)5 * HW];
    int mi = 0;
    for (int o = 6; o < 85; o++) {
        float q = cb[(size_t)o * HW];
        if (q > mx) { mx = q; mi = o - 5; }
    }
    float aw = (a == 0) ? aw0 : ((a == 1) ? aw1 : aw2);
    float ah = (a == 0) ? ah0 : ((a == 1) ? ah1 : ah2);
    float sx = sig_acc(v0), sy = sig_acc(v1);
    float sw2 = 2.0f * sig_acc(v2), sh2 = 2.0f * sig_acc(v3);
    float cx = (2.0f * sx + ((float)gx - 0.5f)) * stride;
    float cy = (2.0f * sy + ((float)gy - 0.5f)) * stride;
    float bw = sw2 * sw2 * aw;
    float bh = sh2 * sh2 * ah;
    float score = sig_acc(v4) * sig_acc(mx);
    float s = (score > 0.15f) ? score : -1.0f;
    u32 fb = __float_as_uint(s);
    u32 m = (fb & 0x80000000u) ? ~fb : (fb | 0x80000000u);
    int gidx = base + (a * ny + gy) * nx + gx;
    size_t gi = (size_t)b * NANCH + gidx;
    float4 bx;
    bx.x = cx - bw * 0.5f; bx.y = cy - bh * 0.5f;
    bx.z = cx + bw * 0.5f; bx.w = cy + bh * 0.5f;
    *(float4*)&boxes_all[gi * 4] = bx;
    keys[gi] = ((u64)m << 32) | (u64)(0xFFFFFFFFu - (u32)gidx);
    cls_all[gi] = mi;
}

// ---------------------------------------------------------------------------
// L5: topk (2 blocks, 1024 thr) || seg1 conv (288 blocks, guarded skeleton)
// ---------------------------------------------------------------------------
union TKU { u32 h[4][2048]; u64 sortb[2048]; };

__global__ __launch_bounds__(1024) void topk_seg1_kernel(
    const u64* __restrict__ keys_all, const float* __restrict__ boxes_all,
    const int* __restrict__ cls_all,
    float* __restrict__ cbox, float* __restrict__ coff,
    float* __restrict__ cscore, int* __restrict__ ccls,
    const unsigned short* __restrict__ r1b, const unsigned short* __restrict__ wp1,
    const float* __restrict__ g_seg1, const float* __restrict__ b_seg1,
    unsigned short* __restrict__ f1, const float* __restrict__ zerobuf,
    float* __restrict__ pbuf)
{
    __shared__ __align__(16) char ms[2 * XBUF];
    __shared__ u32 s_prefix;
    __shared__ int s_rank, s_bin, s_cntgt;
    __shared__ u32 s_cnt;
    if (blockIdx.x >= 2) {
        conv3x3_body((int)blockIdx.x - 2, ms, r1b, wp1, g_seg1, b_seg1, f1, zerobuf,
                     512, 256, 40, 40, 0, 4, pbuf, 1);
        return;
    }
    TKU& sh = *(TKU*)ms;
    int img = blockIdx.x;
    const u64* keys = keys_all + (size_t)img * NANCH;
    int t = threadIdx.x;
    if (t == 0) { s_prefix = 0; s_rank = NCAND; }
    __syncthreads();
    u32 maskdone = 0;
    #pragma unroll 1
    for (int pass = 0; pass < 3; pass++) {
        int shift = (pass == 0) ? 21 : ((pass == 1) ? 10 : 0);
        int nbins = (pass == 2) ? 1024 : 2048;
        for (int i = t; i < 4 * 2048; i += 1024) ((u32*)sh.h)[i] = 0;
        __syncthreads();
        u32 pfx = s_prefix;
        for (int i = t; i < NANCH; i += 1024) {
            u32 u = (u32)(keys[i] >> 32);
            if ((u & maskdone) == pfx) atomicAdd(&sh.h[t & 3][(u >> shift) & (nbins - 1)], 1u);
        }
        __syncthreads();
        for (int i = t; i < nbins; i += 1024)
            sh.h[0][i] = sh.h[0][i] + sh.h[1][i] + sh.h[2][i] + sh.h[3][i];
        __syncthreads();
        u32* A = sh.h[0]; u32* B = sh.h[1];
        for (int st = 1; st < nbins; st <<= 1) {
            for (int i = t; i < nbins; i += 1024)
                B[i] = A[i] + ((i + st < nbins) ? A[i + st] : 0u);
            __syncthreads();
            u32* tmp = A; A = B; B = tmp;
        }
        int rk = s_rank;
        for (int i = t; i < nbins; i += 1024) {
            u32 ge = A[i];
            u32 gt = (i + 1 < nbins) ? A[i + 1] : 0u;
            if (ge >= (u32)rk && gt < (u32)rk) { s_bin = i; s_cntgt = (int)gt; }
        }
        __syncthreads();
        if (t == 0) {
            s_prefix |= ((u32)s_bin) << shift;
            s_rank -= s_cntgt;
        }
        maskdone |= (u32)(nbins - 1) << shift;
        __syncthreads();
    }
    u32 pivot = s_prefix;
    if (t == 0) s_cnt = 0;
    __syncthreads();
    for (int i = t; i < NANCH; i += 1024) {
        u64 k = keys[i]; u32 u = (u32)(k >> 32);
        if (u > pivot) { u32 p = atomicAdd(&s_cnt, 1u); sh.sortb[p] = k; }
    }
    __syncthreads();
    for (int i = t; i < NANCH; i += 1024) {
        u64 k = keys[i]; u32 u = (u32)(k >> 32);
        if (u == pivot) { u32 p = atomicAdd(&s_cnt, 1u); if (p < 2048) sh.sortb[p] = k; }
    }
    __syncthreads();
    u32 nc = s_cnt; if (nc > 2048) nc = 2048;
    for (int i = t; i < 2048; i += 1024) if ((u32)i >= nc) sh.sortb[i] = 0ull;
    __syncthreads();
    for (int k = 2; k <= 2048; k <<= 1) {
        for (int j = k >> 1; j > 0; j >>= 1) {
            __syncthreads();
            for (int i = t; i < 2048; i += 1024) {
                int ixj = i ^ j;
                if (ixj > i) {
                    u64 a = sh.sortb[i], c = sh.sortb[ixj];
                    bool first = ((i & k) == 0);
                    if (first ? (a < c) : (a > c)) { sh.sortb[i] = c; sh.sortb[ixj] = a; }
                }
            }
        }
    }
    __syncthreads();
    for (int i = t; i < NCAND; i += 1024) {
        u64 k = sh.sortb[i];
        u32 u = (u32)(k >> 32);
        u32 fb = (u & 0x80000000u) ? (u ^ 0x80000000u) : ~u;
        float s = __uint_as_float(fb);
        int idx = (int)(0xFFFFFFFFu - (u32)k);
        size_t gi = (size_t)img * NANCH + idx;
        float4 bx = *(const float4*)&boxes_all[gi * 4];
        int cl = cls_all[gi];
        int o = img * NCAND + i;
        *(float4*)&cbox[(size_t)o * 4] = bx;
        float off = (float)cl * 4096.0f;
        float4 ob; ob.x = bx.x + off; ob.y = bx.y + off; ob.z = bx.z + off; ob.w = bx.w + off;
        *(float4*)&coff[(size_t)o * 4] = ob;
        cscore[o] = s;
        ccls[o] = cl;
    }
}

// ---------------------------------------------------------------------------
// L6: nms_mask (126 blocks) || seg combine1 (800 blocks)
// ---------------------------------------------------------------------------
__global__ __launch_bounds__(256) void nmsmask_comb1_kernel(
    const float* __restrict__ coff, u64* __restrict__ maskbuf,
    const float* __restrict__ parts, const float* __restrict__ gain,
    const float* __restrict__ bias, unsigned short* __restrict__ outb)
{
    int blk = blockIdx.x, t = threadIdx.x;
    if (blk >= 126) {
        seg_combine_body((blk - 126) * 256 + t, parts, gain, bias, outb, 4, 2*1600*256/4, 256, 0);
        return;
    }
    int img = blk / 63;
    int tid = (blk % 63) * 256 + t;
    if (tid >= NCAND * 16) return;
    int i = tid >> 4, jw = tid & 15;
    const float* cb = coff + (size_t)img * NCAND * 4;
    float ax1 = cb[i*4+0], ay1 = cb[i*4+1], ax2 = cb[i*4+2], ay2 = cb[i*4+3];
    float aarea = (ax2 - ax1) * (ay2 - ay1);
    u64 bits = 0;
    for (int jj = 0; jj < 64; jj++) {
        int j = jw * 64 + jj;
        if (j >= NCAND) break;
        float bx1 = cb[j*4+0], by1 = cb[j*4+1], bx2 = cb[j*4+2], by2 = cb[j*4+3];
        float barea = (bx2 - bx1) * (by2 - by1);
        float ltx = fmaxf(ax1, bx1), lty = fmaxf(ay1, by1);
        float rbx = fminf(ax2, bx2), rby = fminf(ay2, by2);
        float ww = fmaxf(rbx - ltx, 0.0f), hh = fmaxf(rby - lty, 0.0f);
        float inter = ww * hh;
        float iou = inter / (aarea + barea - inter + 1e-7f);
        if (iou > 0.45f) bits |= (1ull << jj);
    }
    maskbuf[((size_t)img * 1024 + i) * 16 + jw] = bits;
}

// ---------------------------------------------------------------------------
// L7: nms_serial (2 blocks) || resize_add2 (1600 blocks)
// ---------------------------------------------------------------------------
__global__ __launch_bounds__(256) void nmsserial_resize2_kernel(
    const float* __restrict__ cbox, const float* __restrict__ cscore,
    const int* __restrict__ ccls, const u64* __restrict__ maskbuf,
    float* __restrict__ out, float* __restrict__ rois,
    int* __restrict__ lab, float* __restrict__ validf,
    const unsigned short* __restrict__ f1, const unsigned short* __restrict__ x0n,
    unsigned short* __restrict__ r2b)
{
    __shared__ float sS[1024];
    int t = threadIdx.x;
    if (blockIdx.x >= 2) {
        resize_add_body(((int)blockIdx.x - 2) * 256 + t, f1, x0n, r2b, 32, 256, 40, 40, 80, 80);
        return;
    }
    int img = blockIdx.x;
    for (int i = t; i < 1024; i += 256)
        sS[i] = (i < NCAND) ? cscore[img * NCAND + i] : -1.0f;
    __syncthreads();
    if (t >= 64) return;
    int lane = t;
    u64 validw = 0;
    #pragma unroll
    for (int w = 0; w < 16; w++) {
        u64 b = __ballot(sS[w * 64 + lane] > 0.15f);
        if (lane == w) validw = b;
    }
    const u64* mrow = maskbuf + (size_t)img * 1024 * 16;
    int lw = lane & 15;
    u64 rowsel = (lane < 16) ? ~0ull : 0ull;
    u64 suppw = 0, keepw = 0;
    int kcount = 0;
    u64 ring[16];
    #pragma unroll
    for (int k = 0; k < 16; k++) ring[k] = mrow[(size_t)k * 16 + lw];
    for (int ib = 0; ib < 1024; ib += 16) {
        #pragma unroll
        for (int k = 0; k < 16; k++) {
            int i = ib + k;
            u64 row = ring[k];
            ring[k] = mrow[(size_t)((i + 16) & 1023) * 16 + lw];
            int sh = i & 63;
            bool owner_valid = (lane == (i >> 6)) && ((validw >> sh) & 1ull);
            bool mine = owner_valid && !((suppw >> sh) & 1ull);
            u64 bal = __ballot(mine);
            u64 keepall = bal ? ~0ull : 0ull;
            kcount += bal ? 1 : 0;
            suppw |= row & rowsel & keepall;
            keepw |= ((u64)mine) << sh;
        }
        if (kcount >= 100) break;
    }
    int cnt = (lane < 16) ? __popcll(keepw) : 0;
    int pre = 0, total = 0;
    for (int l = 0; l < 16; l++) {
        int c = __shfl(cnt, l);
        if (l < lane) pre += c;
        total += c;
    }
    int kc = total < 100 ? total : 100;
    if (lane < 16) {
        int r = pre;
        u64 kw = keepw;
        while (kw) {
            int b = __ffsll((long long)kw) - 1;
            kw &= kw - 1;
            if (r < 100) {
                int i = lane * 64 + b;
                int ci = img * NCAND + i;
                int slot = img * 100 + r;
                float4 bx = *(const float4*)&cbox[(size_t)ci * 4];
                *(float4*)&out[(size_t)slot * 4] = bx;
                out[800 + slot] = sS[i];
                out[1000 + slot] = (float)(ccls[ci] + 1);
                out[1200 + slot] = 1.0f;
                float4 rv; rv.x = bx.x * 0.125f; rv.y = bx.y * 0.125f; rv.z = bx.z * 0.125f; rv.w = bx.w * 0.125f;
                *(float4*)&rois[(size_t)slot * 4] = rv;
                lab[slot] = ccls[ci];
                validf[slot] = 1.0f;
            }
            r++;
        }
    }
    for (int s = kc + lane; s < 100; s += 64) {
        int slot = img * 100 + s;
        float4 z; z.x = 0; z.y = 0; z.z = 0; z.w = 0;
        *(float4*)&out[(size_t)slot * 4] = z;
        out[800 + slot] = 0.0f;
        out[1000 + slot] = 0.0f;
        out[1200 + slot] = 0.0f;
        *(float4*)&rois[(size_t)slot * 4] = z;
        lab[slot] = 0;
        validf[slot] = 0.0f;
    }
}

// ---------------------------------------------------------------------------
// Fused mask conv v7 (R18 best): 4-way oc split + XCD swizzle + hoisted ptrs.
// ---------------------------------------------------------------------------
#define SC_CHSTRIDE 18432          // 9*2048 shorts per chunk
#define SC_OCBS     73728          // ocb64 stride: 4 chunks * 18432
__global__ __launch_bounds__(256) void mfma_conv_mask(
    const unsigned short* __restrict__ in, const unsigned short* __restrict__ wp,
    const float* __restrict__ gain, const float* __restrict__ bias,
    const float* __restrict__ wml, const int* __restrict__ lab,
    const float* __restrict__ validf,
    int d0, float* __restrict__ pdot, const float* __restrict__ zerobuf)
{
    __shared__ __align__(16) char smem[XBUF];
    __shared__ float wsh[32];
    int id = blockIdx.x;
    int xcd = id & 7;
    int slot = id >> 3;
    int sub = slot & 15;
    int dgrp = slot >> 4;
    int dl = dgrp * 8 + xcd;
    int d = d0 + dl;
    if (validf[d] == 0.0f) return;
    int tile = sub >> 2, oq = sub & 3;
    int tY = tile >> 1, tX = tile & 1;
    int y0 = tY << 4, x0 = tX << 4;
    int oc0 = oq << 5;
    int ocb64 = oc0 >> 6;
    int olocal = oc0 & 63;
    int t = threadIdx.x;
    int lane = t & 63, wv = t >> 6;
    int lg = lane >> 4, lr = lane & 15;
    const unsigned short* inb = in + (size_t)dl * 784 * 128;
    const unsigned short* wpb = wp + (size_t)ocb64 * SC_OCBS;
    int spix = lane >> 2, sg = lane & 3;
    int L = lab[d];
    if (t < 32) wsh[t] = wml[(size_t)L * 128 + oc0 + t];

    const unsigned short* abase[6];
    #pragma unroll
    for (int s = 0; s < 6; s++) {
        int i = wv + s * 4;
        int pix = i * 16 + spix;
        int yy = (pix * 57) >> 10;
        int xx = pix - yy * 18;
        int gy = y0 - 1 + yy, gx = x0 - 1 + xx;
        bool oob = (i >= 21) || (pix >= 324) || (gy < 0) || (gy >= 28) || (gx < 0) || (gx >= 28);
        int gsw = sg ^ swz(pix);
        abase[s] = oob ? (const unsigned short*)zerobuf
                       : inb + (size_t)(gy * 28 + gx) * 128 + gsw * 8;
    }

    f32x4 acc[4][2];
    #pragma unroll
    for (int p = 0; p < 4; p++)
        #pragma unroll
        for (int q = 0; q < 2; q++)
            acc[p][q] = (f32x4){0.f, 0.f, 0.f, 0.f};

    for (int ch = 0; ch < 4; ch++) {
        {
            int c0 = ch << 5;
            char* dst0 = smem + wv * 1024;
            #pragma unroll
            for (int s = 0; s < 6; s++) {
                int i = wv + s * 4;
                if (i < 21) gload16(abase[s] + c0, dst0 + s * 4096);
            }
        }
        __syncthreads();
        const char* sx = smem;
        const unsigned short* wsrc = wpb + (size_t)ch * SC_CHSTRIDE;
        #pragma unroll 3
        for (int tap = 0; tap < 9; tap++) {
            int dy = tap / 3, dx = tap - dy * 3;
            bf16x8 wf[2];
            #pragma unroll
            for (int q = 0; q < 2; q++)
                wf[q] = *(const bf16x8*)(wsrc + (size_t)(tap * 64 + olocal + q * 16 + lr) * 32 + lg * 8);
            #pragma unroll
            for (int p = 0; p < 4; p++) {
                int pix = ((wv << 2) + p + dy) * 18 + dx + lr;
                bf16x8 xf = *(const bf16x8*)(sx + (pix << 6) + ((lg ^ swz(pix)) << 4));
                #pragma unroll
                for (int q = 0; q < 2; q++)
                    acc[p][q] = __builtin_amdgcn_mfma_f32_16x16x32_bf16(wf[q], xf, acc[p][q], 0, 0, 0);
            }
        }
        __syncthreads();
    }
    int x = x0 + lr;
    #pragma unroll
    for (int p = 0; p < 4; p++) {
        int y = y0 + (wv << 2) + p;
        float part = 0.0f;
        #pragma unroll
        for (int q = 0; q < 2; q++) {
            #pragma unroll
            for (int r2 = 0; r2 < 4; r2++) {
                int ol = (q << 4) + (lg << 2) + r2;
                float v = acc[p][q][r2] * gain[oc0 + ol] + bias[oc0 + ol];
                v = silu_fast(v);
                part = fmaf(wsh[ol], v, part);
            }
        }
        part += __shfl_xor(part, 16);
        part += __shfl_xor(part, 32);
        if (lg == 0 && x < 28 && y < 28)
            pdot[((size_t)oq * 200 + d) * 784 + y * 28 + x] = part;
    }
}

// ---------------------------------------------------------------------------
// mask combine: sum the four oc-quarter partial dots + bias, sigmoid, valid
// ---------------------------------------------------------------------------
__global__ void mask_combine_kernel(const float* __restrict__ pdot,
    const float* __restrict__ bml, const int* __restrict__ lab,
    const float* __restrict__ validf, float* __restrict__ out)
{
    int tid = blockIdx.x * 256 + threadIdx.x;
    if (tid >= 200 * 784) return;
    int d = tid / 784;
    if (validf[d] == 0.0f) { out[1400 + tid] = 0.0f; return; }
    const size_t S = (size_t)200 * 784;
    float s = pdot[tid] + pdot[S + tid] + pdot[2 * S + tid] + pdot[3 * S + tid] + bml[lab[d]];
    out[1400 + tid] = 1.0f / (1.0f + __expf(-s));
}

// ---------------------------------------------------------------------------
// ROI-align (28x28) + SiLU, NHWC bf16 in/out, c-inner. Early-exit invalid dets.
// ---------------------------------------------------------------------------
__global__ void roi_silu_kernel(const unsigned short* __restrict__ fseg,
    const float* __restrict__ rois, const float* __restrict__ validf,
    int d0, int total, unsigned short* __restrict__ hbuf)
{
    int tid = blockIdx.x * 256 + threadIdx.x;
    if (tid >= total) return;
    int cg = tid & 15; int r = tid >> 4;
    int p = r % 784; int dl = r / 784;
    int d = d0 + dl; int b = d / 100;
    if (validf[d] == 0.0f) return;
    int py = p / 28, px = p % 28;
    const float* ro = rois + (size_t)d * 4;
    float x1 = ro[0], y1 = ro[1], x2 = ro[2], y2 = ro[3];
    float rw = fmaxf(x2 - x1, 1.0f), rh = fmaxf(y2 - y1, 1.0f);
    float cx = x1 + (((float)px + 0.5f) / 28.0f) * rw;
    float cy = y1 + (((float)py + 0.5f) / 28.0f) * rh;
    cx = fminf(fmaxf(cx, 0.0f), 79.0f);
    cy = fminf(fmaxf(cy, 0.0f), 79.0f);
    int ix0 = (int)floorf(cx), iy0 = (int)floorf(cy);
    int ix1 = min(ix0 + 1, 79), iy1 = min(iy0 + 1, 79);
    float lx = cx - (float)ix0, ly = cy - (float)iy0;
    const unsigned short* fb = fseg + (size_t)b * 6400 * 128 + cg * 8;
    bf16x8 v00 = *(const bf16x8*)&fb[(size_t)(iy0 * 80 + ix0) * 128];
    bf16x8 v01 = *(const bf16x8*)&fb[(size_t)(iy0 * 80 + ix1) * 128];
    bf16x8 v10 = *(const bf16x8*)&fb[(size_t)(iy1 * 80 + ix0) * 128];
    bf16x8 v11 = *(const bf16x8*)&fb[(size_t)(iy1 * 80 + ix1) * 128];
    float w00 = (1.0f - ly) * (1.0f - lx), w01 = (1.0f - ly) * lx;
    float w10 = ly * (1.0f - lx), w11 = ly * lx;
    bf16x8 o;
    #pragma unroll
    for (int j = 0; j < 8; j++) {
        float v = b2f((unsigned short)v00[j]) * w00 + b2f((unsigned short)v01[j]) * w01
                + b2f((unsigned short)v10[j]) * w10 + b2f((unsigned short)v11[j]) * w11;
        o[j] = (short)f2b(silu_fast(v));
    }
    *(bf16x8*)&hbuf[((size_t)dl * 784 + p) * 128 + cg * 8] = o;
}

// ---------------------------------------------------------------------------

extern "C" void kernel_launch(void* const* d_in, const int* in_sizes, int n_in,
                              void* d_out, int out_size, void* d_ws, size_t ws_size,
                              hipStream_t stream)
{
    const float* x0 = (const float*)d_in[0];
    const float* x1 = (const float*)d_in[1];
    const float* x2 = (const float*)d_in[2];
    const float* w_det0 = (const float*)d_in[3];
    const float* b_det0 = (const float*)d_in[4];
    const float* w_det1 = (const float*)d_in[5];
    const float* b_det1 = (const float*)d_in[6];
    const float* w_det2 = (const float*)d_in[7];
    const float* b_det2 = (const float*)d_in[8];
    const float* w_seg0 = (const float*)d_in[9];
    const float* g_seg0 = (const float*)d_in[10];
    const float* b_seg0 = (const float*)d_in[11];
    const float* w_seg1 = (const float*)d_in[12];
    const float* g_seg1 = (const float*)d_in[13];
    const float* b_seg1 = (const float*)d_in[14];
    const float* w_seg2 = (const float*)d_in[15];
    const float* g_seg2 = (const float*)d_in[16];
    const float* b_seg2 = (const float*)d_in[17];
    const float* w_sc = (const float*)d_in[18];
    const float* g_sc = (const float*)d_in[19];
    const float* b_sc = (const float*)d_in[20];
    const float* w_ml = (const float*)d_in[21];
    const float* b_ml = (const float*)d_in[22];
    float* out = (float*)d_out;

    char* ws = (char*)d_ws;
    size_t off = 0;
    auto alloc = [&](size_t bytes) -> void* {
        off = (off + 255) & ~(size_t)255;
        void* p = ws + off;
        off += bytes;
        return p;
    };
    float* co0    = (float*)alloc((size_t)2 * 255 * 6400 * 4);
    float* co1    = (float*)alloc((size_t)2 * 255 * 1600 * 4);
    float* co2    = (float*)alloc((size_t)2 * 255 * 400 * 4);
    float* boxesA = (float*)alloc((size_t)2 * NANCH * 4 * 4);
    u64*   keysA  = (u64*)  alloc((size_t)2 * NANCH * 8);
    int*   clsA   = (int*)  alloc((size_t)2 * NANCH * 4);
    float* cbox   = (float*)alloc((size_t)2 * NCAND * 4 * 4);
    float* coffb  = (float*)alloc((size_t)2 * NCAND * 4 * 4);
    float* cscore = (float*)alloc((size_t)2 * NCAND * 4);
    int*   ccls   = (int*)  alloc((size_t)2 * NCAND * 4);
    u64*   maskb  = (u64*)  alloc((size_t)2 * 1024 * 16 * 8);
    // det transposed weights [C][256]
    float* wdt0   = (float*)alloc((size_t)256 * 256 * 4);
    float* wdt1   = (float*)alloc((size_t)512 * 256 * 4);
    float* wdt2   = (float*)alloc((size_t)1024 * 256 * 4);
    // NHWC bf16 inputs
    unsigned short* x0n = (unsigned short*)alloc((size_t)2 * 6400 * 256 * 2);
    unsigned short* x1n = (unsigned short*)alloc((size_t)2 * 1600 * 512 * 2);
    unsigned short* x2n = (unsigned short*)alloc((size_t)2 * 400 * 1024 * 2);
    // prepped bf16 conv weights
    const size_t s0 = (size_t)512 * 1024 * 9, s1 = (size_t)256 * 512 * 9,
                 s2 = (size_t)128 * 256 * 9,  s3 = (size_t)128 * 128 * 9;
    unsigned short* wprep = (unsigned short*)alloc((s0 + s1 + s2 + s3) * 2);
    // split-K partial buffers: det1+det2 disjoint; seg0 has its OWN buffer
    float* pbuf = (float*)alloc((size_t)4 * 2 * 1600 * 256 * 4);   // 13.1 MB
    float* pbuf2 = pbuf + (size_t)2 * 2 * 255 * 1600;              // det2 region
    float* segp0 = (float*)alloc((size_t)4 * 2 * 400 * 512 * 4);   // 6.6 MB
    // seg chain (NHWC bf16)
    unsigned short* f0   = (unsigned short*)alloc((size_t)2 * 400 * 512 * 2);
    unsigned short* r1b  = (unsigned short*)alloc((size_t)2 * 1600 * 512 * 2);
    unsigned short* f1   = (unsigned short*)alloc((size_t)2 * 1600 * 256 * 2);
    unsigned short* r2b  = (unsigned short*)alloc((size_t)2 * 6400 * 256 * 2);
    unsigned short* fseg = (unsigned short*)alloc((size_t)2 * 6400 * 128 * 2);
    float* zerobuf = (float*)alloc(2048);
    float* roisW  = (float*)alloc((size_t)200 * 4 * 4);
    int*   labW   = (int*)  alloc((size_t)200 * 4);
    float* validW = (float*)alloc((size_t)200 * 4);
    float* pdot   = (float*)alloc((size_t)4 * 200 * 784 * 4);   // 2.5 MB
    unsigned short* hbuf   = (unsigned short*)alloc((size_t)200 * 784 * 128 * 2);

    int DCH = 200;
    if (off > ws_size) {
        DCH = 25;
        hbuf = (unsigned short*)co0;
    }

    // --- 1. merged prep ---
    prep_all_kernel<<<4289, 256, 0, stream>>>(
        w_det0, w_det1, w_det2, wdt0, wdt1, wdt2,
        w_seg0, w_seg1, w_seg2, w_sc,
        wprep, wprep + s0, wprep + s0 + s1, wprep + s0 + s1 + s2,
        x0, x1, x2, x0n, x1n, x2n, zerobuf);

    // --- 2. det convs || seg0 conv (single-buffered; LDS max 40960 -> 4/CU) ---
    detseg_conv_kernel<<<2048, 256, 0, stream>>>(
        x0, wdt0, b_det0, co0,
        x1, wdt1, b_det1, pbuf,
        x2, wdt2, b_det2, pbuf2,
        x2n, wprep, g_seg0, b_seg0, f0, zerobuf, segp0);

    // --- 3. det combines || seg combine0 ---
    combine_both_kernel<<<1397, 256, 0, stream>>>(pbuf, b_det1, co1, pbuf2, b_det2, co2,
                                                  segp0, g_seg0, b_seg0, f0);

    // --- 4. decode || resize_add1 ---
    decode_resize1_kernel<<<998, 256, 0, stream>>>(co0, co1, co2, boxesA, keysA, clsA,
                                                   f0, x1n, r1b);

    // --- 5. topk || seg1 conv ---
    topk_seg1_kernel<<<290, 1024, 0, stream>>>(keysA, boxesA, clsA,
        cbox, coffb, cscore, ccls,
        r1b, wprep + s0, g_seg1, b_seg1, f1, zerobuf, pbuf);

    // --- 6. nms_mask || seg combine1 ---
    nmsmask_comb1_kernel<<<926, 256, 0, stream>>>(coffb, maskb,
        pbuf, g_seg1, b_seg1, f1);

    // --- 7. nms_serial || resize_add2 ---
    nmsserial_resize2_kernel<<<1602, 256, 0, stream>>>(cbox, cscore, ccls, maskb,
        out, roisW, labW, validW, f1, x0n, r2b);

    // --- 8-9. seg2 conv + combine2 ---
    mfma_conv3x3<<<208, 256, 0, stream>>>(r2b, wprep + s0 + s1, g_seg2, b_seg2, fseg, zerobuf, 256, 128, 80, 80, 0, 2, pbuf);
    seg_combine_kernel<<<1600, 256, 0, stream>>>(pbuf, g_seg2, b_seg2, fseg, 2, 2*6400*128/4, 128, 0);

    // --- 10-12. mask branch ---
    for (int d0i = 0; d0i < 200; d0i += DCH) {
        int total = DCH * 784 * 16;
        roi_silu_kernel<<<(total + 255) / 256, 256, 0, stream>>>(fseg, roisW, validW, d0i, total, hbuf);
        mfma_conv_mask<<<DCH * 16, 256, 0, stream>>>(hbuf, wprep + s0 + s1 + s2,
            g_sc, b_sc, w_ml, labW, validW, d0i, pdot, zerobuf);
    }
    mask_combine_kernel<<<(200 * 784 + 255) / 256, 256, 0, stream>>>(pdot, b_ml, labW, validW, out);
}

// Round 25
// 364.757 us; speedup vs baseline: 1.0136x; 1.0136x over previous
//
#include <hip/hip_runtime.h>
#include <hip/hip_bf16.h>

typedef unsigned int u32;
typedef unsigned long long u64;
typedef short bf16x8 __attribute__((ext_vector_type(8)));
typedef float f32x4 __attribute__((ext_vector_type(4)));

#define NCAND 1000
#define NANCH 25200

__device__ __forceinline__ float sig_acc(float x) { return 1.0f / (1.0f + expf(-x)); }
__device__ __forceinline__ float silu_fast(float v) { return v / (1.0f + __expf(-v)); }
__device__ __forceinline__ unsigned short f2b(float f) {
    __hip_bfloat16 h = __float2bfloat16(f);
    return *reinterpret_cast<unsigned short*>(&h);
}
__device__ __forceinline__ float b2f(unsigned short u) {
    return __uint_as_float(((u32)u) << 16);
}
__device__ __forceinline__ int swz(int p) { return (p & 3) ^ ((p >> 2) & 3); }

// async global->LDS, 16B per lane; dst = wave-uniform base + lane*16
__device__ __forceinline__ void gload16(const void* g, void* l) {
    __builtin_amdgcn_global_load_lds((const __attribute__((address_space(1))) void*)g,
                                     (__attribute__((address_space(3))) void*)l, 16, 0, 0);
}

// ---------------------------------------------------------------------------
// Merged prep (R20): wdt transposes + zerobuf + wprep + NCHW->NHWC in 1 launch
// ---------------------------------------------------------------------------
__global__ __launch_bounds__(256) void prep_all_kernel(
    const float* __restrict__ w_det0, const float* __restrict__ w_det1, const float* __restrict__ w_det2,
    float* __restrict__ wdt0, float* __restrict__ wdt1, float* __restrict__ wdt2,
    const float* __restrict__ w_seg0, const float* __restrict__ w_seg1,
    const float* __restrict__ w_seg2, const float* __restrict__ w_sc,
    unsigned short* __restrict__ wp0, unsigned short* __restrict__ wp1,
    unsigned short* __restrict__ wp2, unsigned short* __restrict__ wp3,
    const float* __restrict__ x0, const float* __restrict__ x1, const float* __restrict__ x2,
    unsigned short* __restrict__ x0n, unsigned short* __restrict__ x1n, unsigned short* __restrict__ x2n,
    float* __restrict__ zerobuf)
{
    __shared__ float tile[64][65];
    int b = blockIdx.x, t = threadIdx.x;
    if (b < 112) {
        const float* w; float* wdt; int C, c0, oc0;
        if (b < 16)      { w = w_det0; wdt = wdt0; C = 256;  c0 = (b & 3) * 64;  oc0 = (b >> 2) * 64; }
        else if (b < 48) { int l = b - 16; w = w_det1; wdt = wdt1; C = 512;  c0 = (l & 7) * 64;  oc0 = (l >> 3) * 64; }
        else             { int l = b - 48; w = w_det2; wdt = wdt2; C = 1024; c0 = (l & 15) * 64; oc0 = (l >> 4) * 64; }
        for (int k = t; k < 1024; k += 256) {
            int oo = k >> 4, q = k & 15;
            int oc = oc0 + oo;
            float4 v = {0.f, 0.f, 0.f, 0.f};
            if (oc < 255) v = *(const float4*)&w[(size_t)oc * C + c0 + q * 4];
            tile[oo][q * 4 + 0] = v.x; tile[oo][q * 4 + 1] = v.y;
            tile[oo][q * 4 + 2] = v.z; tile[oo][q * 4 + 3] = v.w;
        }
        __syncthreads();
        for (int k = t; k < 1024; k += 256) {
            int cc = k >> 4, q = k & 15;
            float4 o;
            o.x = tile[q * 4 + 0][cc]; o.y = tile[q * 4 + 1][cc];
            o.z = tile[q * 4 + 2][cc]; o.w = tile[q * 4 + 3][cc];
            *(float4*)&wdt[(size_t)(c0 + cc) * 256 + oc0 + q * 4] = o;
        }
    } else if (b == 112) {
        zerobuf[t] = 0.0f; zerobuf[t + 256] = 0.0f;
    } else if (b < 2865) {
        int l = b - 113;
        const float* w; unsigned short* dst; int Cin, Cout;
        if (l < 2048)      { w = w_seg0; dst = wp0; Cin = 1024; Cout = 512; }
        else if (l < 2560) { l -= 2048; w = w_seg1; dst = wp1; Cin = 512; Cout = 256; }
        else if (l < 2688) { l -= 2560; w = w_seg2; dst = wp2; Cin = 256; Cout = 128; }
        else               { l -= 2688; w = w_sc;  dst = wp3; Cin = 128; Cout = 128; }
        int i = l * 256 + t;
        if (i < Cout * Cin) {
            int oc = i / Cin, c = i - oc * Cin;
            int nch = Cin >> 5;
            int ocb = oc >> 6, ocl = oc & 63, chn = c >> 5, cl = c & 31;
            const float* src = w + (size_t)i * 9;
            size_t base = (((size_t)(ocb * nch + chn) * 9) * 64 + ocl) * 32 + cl;
            #pragma unroll
            for (int tap = 0; tap < 9; tap++)
                dst[base + (size_t)tap * 2048] = f2b(src[tap]);
        }
    } else {
        int l = b - 2865;
        const float* x; unsigned short* y; int C, HW, n, c0, p0;
        if (l < 800)       { x = x0; y = x0n; C = 256;  HW = 6400; p0 = (l % 100) * 64; c0 = ((l / 100) & 3) * 64; n = l / 400; }
        else if (l < 1200) { l -= 800;  x = x1; y = x1n; C = 512;  HW = 1600; p0 = (l % 25) * 64; c0 = ((l / 25) & 7) * 64; n = l / 200; }
        else               { l -= 1200; x = x2; y = x2n; C = 1024; HW = 400;  p0 = (l % 7) * 64;  c0 = ((l / 7) & 15) * 64; n = l / 112; }
        const float* xb = x + ((size_t)n * C + c0) * HW;
        for (int k = t; k < 1024; k += 256) {
            int cc = k >> 4, q = k & 15;
            int gp = p0 + q * 4;
            float4 v = {0.f, 0.f, 0.f, 0.f};
            if (gp < HW) v = *(const float4*)&xb[(size_t)cc * HW + gp];
            tile[cc][q * 4 + 0] = v.x; tile[cc][q * 4 + 1] = v.y;
            tile[cc][q * 4 + 2] = v.z; tile[cc][q * 4 + 3] = v.w;
        }
        __syncthreads();
        for (int k = t; k < 512; k += 256) {
            int pp = k >> 3, cg = k & 7;
            int gp = p0 + pp;
            if (gp < HW) {
                bf16x8 pk;
                #pragma unroll
                for (int j = 0; j < 8; j++) pk[j] = (short)f2b(tile[cg * 8 + j][pp]);
                *(bf16x8*)&y[((size_t)n * HW + gp) * C + c0 + cg * 8] = pk;
            }
        }
    }
}

// ---------------------------------------------------------------------------
// Det 1x1 conv body (XCD-swizzled), smem passed in. xs 32KB + wsm 8KB = 40KB.
// ---------------------------------------------------------------------------
#define XBUF 21504
__device__ __forceinline__ void det_conv_body(int id, char* smembase,
    const float* __restrict__ x, const float* __restrict__ wdt, const float* __restrict__ bias,
    float* __restrict__ dst, int C, int HW, int c_len, int nsl)
{
    typedef float XS[32][128];
    typedef float WS[32][32];
    XS* xs = (XS*)smembase;
    WS* wsm = (WS*)(smembase + 32768);
    int nx = (HW + 127) >> 7;
    int ngroups = nx * nsl * 2;
    int xcd = id & 7;
    int rest = id >> 3;
    int sub = rest & 7;
    int dgrp = rest >> 3;
    int gidx = dgrp * 8 + xcd;
    if (gidx >= ngroups) return;
    int px = gidx % nx;
    int r0 = gidx / nx;
    int slice = r0 % nsl;
    int b = r0 / nsl;
    int oc0 = sub * 32;
    int px0 = px * 128;
    int c0base = slice * c_len;
    int t = threadIdx.x;
    int lane = t & 63, wv = t >> 6;
    int pxg = t & 31, og = t >> 5;
    int lpx = pxg << 2;
    bool full = (px0 + 128 <= HW);
    const float* xb = x + (size_t)b * C * HW;

    auto stage = [&](int c0, int nb) {
        if (full) {
            for (int i = wv; i < 16; i += 4) {
                const float* src = xb + (size_t)(c0 + 2 * i + (lane >> 5)) * HW + px0 + (lane & 31) * 4;
                gload16(src, &xs[nb][2 * i][0]);
            }
        } else {
            for (int k = t; k < 4096; k += 256) {
                int cc = k >> 7, pp = k & 127;
                int gp = px0 + pp;
                xs[nb][cc][pp] = (gp < HW) ? xb[(size_t)(c0 + cc) * HW + gp] : 0.0f;
            }
        }
        const float* wsrc = wdt + (size_t)(c0 + 8 * wv + (lane >> 3)) * 256 + oc0 + (lane & 7) * 4;
        gload16(wsrc, &wsm[nb][8 * wv][0]);
    };

    float acc[4][4] = {{0.f,0.f,0.f,0.f},{0.f,0.f,0.f,0.f},{0.f,0.f,0.f,0.f},{0.f,0.f,0.f,0.f}};
    int nchk = c_len >> 5;
    stage(c0base, 0);
    __syncthreads();
    int nb = 0;
    for (int ch = 0; ch < nchk; ch++) {
        if (ch + 1 < nchk) stage(c0base + ((ch + 1) << 5), nb ^ 1);
        #pragma unroll 8
        for (int cc = 0; cc < 32; cc++) {
            float4 xv = *(const float4*)&xs[nb][cc][lpx];
            float4 wv4 = *(const float4*)&wsm[nb][cc][og << 2];
            float xr[4] = {xv.x, xv.y, xv.z, xv.w};
            float wr[4] = {wv4.x, wv4.y, wv4.z, wv4.w};
            #pragma unroll
            for (int oo = 0; oo < 4; oo++)
                #pragma unroll
                for (int j = 0; j < 4; j++)
                    acc[oo][j] = fmaf(wr[oo], xr[j], acc[oo][j]);
        }
        __syncthreads();
        nb ^= 1;
    }
    float* outb = dst + (size_t)slice * ((size_t)2 * 255 * HW);
    int gp = px0 + lpx;
    #pragma unroll
    for (int oo = 0; oo < 4; oo++) {
        int oc = oc0 + (og << 2) + oo;
        if (oc >= 255) continue;
        float bv = (nsl == 1) ? bias[oc] : 0.0f;
        float* ob = outb + ((size_t)b * 255 + oc) * HW;
        if (gp + 3 < HW) {
            float4 v; v.x = acc[oo][0]+bv; v.y = acc[oo][1]+bv; v.z = acc[oo][2]+bv; v.w = acc[oo][3]+bv;
            *(float4*)&ob[gp] = v;
        } else {
            for (int j = 0; j < 4; j++) if (gp + j < HW) ob[gp + j] = acc[oo][j] + bv;
        }
    }
}

// ---------------------------------------------------------------------------
// bf16 MFMA 3x3 conv body (R19 XCD-swizzled), guarded-skeleton form.
// dbuf=1: double-buffered (43KB). dbuf=0: single-buffered (21.5KB).
// ---------------------------------------------------------------------------
__device__ __forceinline__ void conv3x3_body(int id, char* smem,
    const unsigned short* __restrict__ in, const unsigned short* __restrict__ wp,
    const float* __restrict__ gain, const float* __restrict__ bias,
    unsigned short* __restrict__ out, const float* __restrict__ zerobuf,
    int Cin, int Cout, int H, int W, int act, int ksl, float* __restrict__ pout,
    int dbuf)
{
    bool on = (threadIdx.x < 256);
    int tilesX = (W + 15) >> 4;
    int tilesY = (H + 15) >> 4;
    int tiles = tilesX * tilesY;
    int nocb = Cout >> 6;
    int ngroups = tiles * ksl * 2;
    int xcd = id & 7;
    int rest = id >> 3;
    int sub = rest % nocb;
    int dgrp = rest / nocb;
    int gidx = dgrp * 8 + xcd;
    if (gidx >= ngroups) return;            // block-uniform
    int tile = gidx % tiles;
    int r0 = gidx / tiles;
    int slice = r0 % ksl;
    int n = r0 / ksl;
    int ocb = sub;
    int tY = tile / tilesX, tX = tile - tY * tilesX;
    int y0 = tY << 4, x0 = tX << 4;
    int oc0 = ocb << 6;
    int t = threadIdx.x;
    int lane = t & 63, wv = t >> 6;
    int lg = lane >> 4, lr = lane & 15;
    int HW = H * W;
    int nch = Cin >> 5;
    int nchunks = nch / ksl;
    int chbase = slice * nchunks;
    const unsigned short* inb = in + (size_t)n * HW * Cin;
    const unsigned short* wpb = wp + (size_t)ocb * ((size_t)nch * 9 * 2048);
    int spix = lane >> 2, sg = lane & 3;

    f32x4 acc[4][4];
    #pragma unroll
    for (int p = 0; p < 4; p++)
        #pragma unroll
        for (int q = 0; q < 4; q++)
            acc[p][q] = (f32x4){0.f, 0.f, 0.f, 0.f};

    auto stageX = [&](int ch, int nbuf) {
        int c0 = ch << 5;
        char* dst0 = smem + nbuf * XBUF;
        for (int i = wv; i < 21; i += 4) {
            int pix = i * 16 + spix;
            int yy = (pix * 57) >> 10;          // pix/18, exact for pix<=335
            int xx = pix - yy * 18;
            int gy = y0 - 1 + yy, gx = x0 - 1 + xx;
            bool oob = (pix >= 324) || (gy < 0) || (gy >= H) || (gx < 0) || (gx >= W);
            int gsw = sg ^ swz(pix);
            const void* src = oob ? (const void*)zerobuf
                : (const void*)(inb + (size_t)(gy * W + gx) * Cin + c0 + gsw * 8);
            gload16(src, dst0 + i * 1024);
        }
    };

    auto compute = [&](const char* sx, int ch) {
        const unsigned short* wsrc = wpb + (size_t)ch * (9 * 2048);
        #pragma unroll 3
        for (int tap = 0; tap < 9; tap++) {
            int dy = tap / 3, dx = tap - dy * 3;
            bf16x8 wf[4];
            #pragma unroll
            for (int q = 0; q < 4; q++)
                wf[q] = *(const bf16x8*)(wsrc + (size_t)(tap * 64 + q * 16 + lr) * 32 + lg * 8);
            #pragma unroll
            for (int p = 0; p < 4; p++) {
                int pix = ((wv << 2) + p + dy) * 18 + dx + lr;
                bf16x8 xf = *(const bf16x8*)(sx + (pix << 6) + ((lg ^ swz(pix)) << 4));
                #pragma unroll
                for (int q = 0; q < 4; q++)
                    acc[p][q] = __builtin_amdgcn_mfma_f32_16x16x32_bf16(wf[q], xf, acc[p][q], 0, 0, 0);
            }
        }
    };

    if (dbuf) {
        if (on) stageX(chbase, 0);
        __syncthreads();
        int nb = 0;
        for (int ci = 0; ci < nchunks; ci++) {
            int ch = chbase + ci;
            if (on && ci + 1 < nchunks) stageX(ch + 1, nb ^ 1);
            if (on) compute(smem + nb * XBUF, ch);
            __syncthreads();
            nb ^= 1;
        }
    } else {
        for (int ci = 0; ci < nchunks; ci++) {
            int ch = chbase + ci;
            if (on) stageX(ch, 0);
            __syncthreads();            // drains gload_lds
            if (on) compute(smem, ch);
            __syncthreads();
        }
    }
    if (!on) return;
    int x = x0 + lr;
    if (x >= W) return;
    if (ksl == 1) {
        #pragma unroll
        for (int p = 0; p < 4; p++) {
            int y = y0 + (wv << 2) + p;
            if (y >= H) continue;
            unsigned short* ob = out + ((size_t)n * HW + (size_t)y * W + x) * Cout + oc0;
            #pragma unroll
            for (int q = 0; q < 4; q++) {
                int obase = (q << 4) + (lg << 2);
                ushort4 pk;
                #pragma unroll
                for (int r2 = 0; r2 < 4; r2++) {
                    int oc = oc0 + obase + r2;
                    float v = acc[p][q][r2] * gain[oc] + bias[oc];
                    if (act) v = silu_fast(v);
                    ((unsigned short*)&pk)[r2] = f2b(v);
                }
                *(ushort4*)&ob[obase] = pk;
            }
        }
    } else {
        float* pb = pout + ((size_t)(slice * 2 + n) * HW) * Cout;
        #pragma unroll
        for (int p = 0; p < 4; p++) {
            int y = y0 + (wv << 2) + p;
            if (y >= H) continue;
            float* ob = pb + ((size_t)y * W + x) * Cout + oc0;
            #pragma unroll
            for (int q = 0; q < 4; q++)
                *(f32x4*)&ob[(q << 4) + (lg << 2)] = acc[p][q];
        }
    }
}

__global__ __launch_bounds__(256) void mfma_conv3x3(
    const unsigned short* __restrict__ in, const unsigned short* __restrict__ wp,
    const float* __restrict__ gain, const float* __restrict__ bias,
    unsigned short* __restrict__ out, const float* __restrict__ zerobuf,
    int Cin, int Cout, int H, int W, int act, int ksl, float* __restrict__ pout)
{
    __shared__ __align__(16) char smem[2 * XBUF];
    conv3x3_body(blockIdx.x, smem, in, wp, gain, bias, out, zerobuf, Cin, Cout, H, W, act, ksl, pout, 1);
}

// ---------------------------------------------------------------------------
// L2: seg0 conv || det convs. R24 post-mortem: blocks dispatch in ID order,
// and with 2048 blocks > ~1024 resident slots the LAST range serializes
// behind the others. seg0 goes FIRST so it lands in generation 1 and truly
// overlaps with det; det ranges keep base%8==0 for the XCD swizzle.
// [0,256) seg0 | [256,1088) det0 | [1088,1536) det1 | [1536,2048) det2
// ---------------------------------------------------------------------------
__global__ __launch_bounds__(256) void detseg_conv_kernel(
    const float* __restrict__ xa, const float* __restrict__ wdta, const float* __restrict__ ba, float* __restrict__ da,
    const float* __restrict__ xb2, const float* __restrict__ wdtb, const float* __restrict__ bb, float* __restrict__ db,
    const float* __restrict__ xc, const float* __restrict__ wdtc, const float* __restrict__ bc, float* __restrict__ dc,
    const unsigned short* __restrict__ x2n, const unsigned short* __restrict__ wp0,
    const float* __restrict__ g_seg0, const float* __restrict__ b_seg0,
    unsigned short* __restrict__ f0, const float* __restrict__ zerobuf, float* __restrict__ segp0)
{
    __shared__ __align__(16) char smem[40960];
    int blk = blockIdx.x;
    if (blk < 256)       conv3x3_body(blk, smem, x2n, wp0, g_seg0, b_seg0, f0, zerobuf, 1024, 512, 20, 20, 0, 4, segp0, 0);
    else if (blk < 1088) det_conv_body(blk - 256, smem, xa, wdta, ba, da, 256, 6400, 256, 1);
    else if (blk < 1536) det_conv_body(blk - 1088, smem, xb2, wdtb, bb, db, 512, 1600, 256, 2);
    else                 det_conv_body(blk - 1536, smem, xc, wdtc, bc, dc, 1024, 400, 128, 8);
}

// ---------------------------------------------------------------------------
// seg split-K combine body
// ---------------------------------------------------------------------------
__device__ __forceinline__ void seg_combine_body(int tid, const float* __restrict__ parts,
    const float* __restrict__ gain, const float* __restrict__ bias,
    unsigned short* __restrict__ out, int nsl, int total4, int C, int act)
{
    if (tid >= total4) return;
    size_t stride = (size_t)total4 * 4;
    float4 s = {0.f, 0.f, 0.f, 0.f};
    for (int sl = 0; sl < nsl; sl++) {
        float4 v = *(const float4*)&parts[sl * stride + (size_t)tid * 4];
        s.x += v.x; s.y += v.y; s.z += v.z; s.w += v.w;
    }
    int oc = (tid * 4) % C;
    float r[4] = {s.x, s.y, s.z, s.w};
    ushort4 pk;
    #pragma unroll
    for (int j = 0; j < 4; j++) {
        float v = r[j] * gain[oc + j] + bias[oc + j];
        if (act) v = silu_fast(v);
        ((unsigned short*)&pk)[j] = f2b(v);
    }
    *(ushort4*)&out[(size_t)tid * 4] = pk;
}

__global__ void seg_combine_kernel(const float* __restrict__ parts,
    const float* __restrict__ gain, const float* __restrict__ bias,
    unsigned short* __restrict__ out, int nsl, int total4, int C, int act)
{
    seg_combine_body(blockIdx.x * 256 + threadIdx.x, parts, gain, bias, out, nsl, total4, C, act);
}

// ---------------------------------------------------------------------------
// L3: det split-K combine (both heads) || seg combine0.
// [0,797) det1 | [797,997) det2 | [997,1397) comb0
// ---------------------------------------------------------------------------
__global__ void combine_both_kernel(
    const float* __restrict__ p1, const float* __restrict__ b1, float* __restrict__ co1,
    const float* __restrict__ p2, const float* __restrict__ b2, float* __restrict__ co2,
    const float* __restrict__ segp0, const float* __restrict__ g_seg0,
    const float* __restrict__ b_seg0, unsigned short* __restrict__ f0)
{
    int b = blockIdx.x, t = threadIdx.x;
    if (b >= 997) {
        seg_combine_body((b - 997) * 256 + t, segp0, g_seg0, b_seg0, f0, 4, 2*400*512/4, 512, 0);
        return;
    }
    const float* parts; const float* bias; float* co; int nsl, HW, tid, total4;
    if (b < 797) { parts = p1; bias = b1; co = co1; nsl = 2; HW = 1600; tid = b * 256 + t; total4 = 2 * 255 * 1600 / 4; }
    else         { parts = p2; bias = b2; co = co2; nsl = 8; HW = 400;  tid = (b - 797) * 256 + t; total4 = 2 * 255 * 400 / 4; }
    if (tid >= total4) return;
    size_t stride = (size_t)2 * 255 * HW;
    float4 s = {0.f, 0.f, 0.f, 0.f};
    for (int sl = 0; sl < nsl; sl++) {
        float4 v = *(const float4*)&parts[sl * stride + (size_t)tid * 4];
        s.x += v.x; s.y += v.y; s.z += v.z; s.w += v.w;
    }
    int oc = ((tid * 4) / HW) % 255;
    float bv = bias[oc];
    s.x += bv; s.y += bv; s.z += bv; s.w += bv;
    *(float4*)&co[(size_t)tid * 4] = s;
}

// ---------------------------------------------------------------------------
// resize body
// ---------------------------------------------------------------------------
__device__ __forceinline__ void resize_add_body(int tid, const unsigned short* __restrict__ f,
    const unsigned short* __restrict__ skip, unsigned short* __restrict__ out,
    int C8, int C, int IH, int IW, int OH, int OW)
{
    int total = 2 * OH * OW * C8;
    if (tid >= total) return;
    int cg = tid % C8; int r = tid / C8;
    int ox = r % OW; r /= OW;
    int oy = r % OH; int n = r / OH;
    float sy = (float)(IH - 1) / (float)(OH - 1);
    float sx = (float)(IW - 1) / (float)(OW - 1);
    float ys = oy * sy, xs = ox * sx;
    int y0 = (int)floorf(ys); if (y0 > IH - 1) y0 = IH - 1;
    int x0 = (int)floorf(xs); if (x0 > IW - 1) x0 = IW - 1;
    int y1 = min(y0 + 1, IH - 1), x1 = min(x0 + 1, IW - 1);
    float fy = ys - (float)y0, fx = xs - (float)x0;
    const unsigned short* fb = f + (size_t)n * IH * IW * C + cg * 8;
    bf16x8 a00 = *(const bf16x8*)&fb[(size_t)(y0 * IW + x0) * C];
    bf16x8 a01 = *(const bf16x8*)&fb[(size_t)(y0 * IW + x1) * C];
    bf16x8 a10 = *(const bf16x8*)&fb[(size_t)(y1 * IW + x0) * C];
    bf16x8 a11 = *(const bf16x8*)&fb[(size_t)(y1 * IW + x1) * C];
    bf16x8 sk = *(const bf16x8*)&skip[(size_t)tid * 8];
    bf16x8 o;
    #pragma unroll
    for (int j = 0; j < 8; j++) {
        float r0 = b2f((unsigned short)a00[j]) * (1.0f - fy) + b2f((unsigned short)a10[j]) * fy;
        float r1 = b2f((unsigned short)a01[j]) * (1.0f - fy) + b2f((unsigned short)a11[j]) * fy;
        float v = r0 * (1.0f - fx) + r1 * fx + b2f((unsigned short)sk[j]);
        o[j] = (short)f2b(v);
    }
    *(bf16x8*)&out[(size_t)tid * 8] = o;
}

// ---------------------------------------------------------------------------
// L4: decode (198 blocks) || resize_add1 (800 blocks)
// ---------------------------------------------------------------------------
__global__ void decode_resize1_kernel(const float* __restrict__ co0, const float* __restrict__ co1,
    const float* __restrict__ co2, float* __restrict__ boxes_all, u64* __restrict__ keys,
    int* __restrict__ cls_all,
    const unsigned short* __restrict__ f0, const unsigned short* __restrict__ x1n,
    unsigned short* __restrict__ r1b)
{
    int blk = blockIdx.x, t = threadIdx.x;
    if (blk >= 198) {
        resize_add_body((blk - 198) * 256 + t, f0, x1n, r1b, 64, 512, 20, 20, 40, 40);
        return;
    }
    const float* conv; int ny, base, total; float stride;
    float aw0, ah0, aw1, ah1, aw2, ah2;
    int tid;
    if (blk < 150) {
        conv = co0; ny = 80; stride = 8.0f; base = 0; total = 38400;
        aw0 = 10.f; ah0 = 13.f; aw1 = 16.f; ah1 = 30.f; aw2 = 33.f; ah2 = 23.f;
        tid = blk * 256 + t;
    } else if (blk < 188) {
        conv = co1; ny = 40; stride = 16.0f; base = 19200; total = 9600;
        aw0 = 30.f; ah0 = 61.f; aw1 = 62.f; ah1 = 45.f; aw2 = 59.f; ah2 = 119.f;
        tid = (blk - 150) * 256 + t;
    } else {
        conv = co2; ny = 20; stride = 32.0f; base = 24000; total = 2400;
        aw0 = 116.f; ah0 = 90.f; aw1 = 156.f; ah1 = 198.f; aw2 = 373.f; ah2 = 326.f;
        tid = (blk - 188) * 256 + t;
    }
    if (tid >= total) return;
    int nx = ny;
    int HW = ny * nx;
    int gx = tid % nx; int r = tid / nx;
    int gy = r % ny; r /= ny;
    int a = r % 3; int b = r / 3;
    const float* cb = conv + ((size_t)b * 255 + a * 85) * HW + (size_t)gy * nx + gx;
    float v0 = cb[0];
    float v1 = cb[(size_t)1 * HW];
    float v2 = cb[(size_t)2 * HW];
    float v3 = cb[(size_t)3 * HW];
    float v4 = cb[(size_t)4 * HW];
    float mx = cb[(size_t)5 * HW];
    int mi = 0;
    for (int o = 6; o < 85; o++) {
        float q = cb[(size_t)o * HW];
        if (q > mx) { mx = q; mi = o - 5; }
    }
    float aw = (a == 0) ? aw0 : ((a == 1) ? aw1 : aw2);
    float ah = (a == 0) ? ah0 : ((a == 1) ? ah1 : ah2);
    float sx = sig_acc(v0), sy = sig_acc(v1);
    float sw2 = 2.0f * sig_acc(v2), sh2 = 2.0f * sig_acc(v3);
    float cx = (2.0f * sx + ((float)gx - 0.5f)) * stride;
    float cy = (2.0f * sy + ((float)gy - 0.5f)) * stride;
    float bw = sw2 * sw2 * aw;
    float bh = sh2 * sh2 * ah;
    float score = sig_acc(v4) * sig_acc(mx);
    float s = (score > 0.15f) ? score : -1.0f;
    u32 fb = __float_as_uint(s);
    u32 m = (fb & 0x80000000u) ? ~fb : (fb | 0x80000000u);
    int gidx = base + (a * ny + gy) * nx + gx;
    size_t gi = (size_t)b * NANCH + gidx;
    float4 bx;
    bx.x = cx - bw * 0.5f; bx.y = cy - bh * 0.5f;
    bx.z = cx + bw * 0.5f; bx.w = cy + bh * 0.5f;
    *(float4*)&boxes_all[gi * 4] = bx;
    keys[gi] = ((u64)m << 32) | (u64)(0xFFFFFFFFu - (u32)gidx);
    cls_all[gi] = mi;
}

// ---------------------------------------------------------------------------
// L5: topk (2 blocks, 1024 thr) || seg1 conv (288 blocks, guarded skeleton)
// ---------------------------------------------------------------------------
union TKU { u32 h[4][2048]; u64 sortb[2048]; };

__global__ __launch_bounds__(1024) void topk_seg1_kernel(
    const u64* __restrict__ keys_all, const float* __restrict__ boxes_all,
    const int* __restrict__ cls_all,
    float* __restrict__ cbox, float* __restrict__ coff,
    float* __restrict__ cscore, int* __restrict__ ccls,
    const unsigned short* __restrict__ r1b, const unsigned short* __restrict__ wp1,
    const float* __restrict__ g_seg1, const float* __restrict__ b_seg1,
    unsigned short* __restrict__ f1, const float* __restrict__ zerobuf,
    float* __restrict__ pbuf)
{
    __shared__ __align__(16) char ms[2 * XBUF];
    __shared__ u32 s_prefix;
    __shared__ int s_rank, s_bin, s_cntgt;
    __shared__ u32 s_cnt;
    if (blockIdx.x >= 2) {
        conv3x3_body((int)blockIdx.x - 2, ms, r1b, wp1, g_seg1, b_seg1, f1, zerobuf,
                     512, 256, 40, 40, 0, 4, pbuf, 1);
        return;
    }
    TKU& sh = *(TKU*)ms;
    int img = blockIdx.x;
    const u64* keys = keys_all + (size_t)img * NANCH;
    int t = threadIdx.x;
    if (t == 0) { s_prefix = 0; s_rank = NCAND; }
    __syncthreads();
    u32 maskdone = 0;
    #pragma unroll 1
    for (int pass = 0; pass < 3; pass++) {
        int shift = (pass == 0) ? 21 : ((pass == 1) ? 10 : 0);
        int nbins = (pass == 2) ? 1024 : 2048;
        for (int i = t; i < 4 * 2048; i += 1024) ((u32*)sh.h)[i] = 0;
        __syncthreads();
        u32 pfx = s_prefix;
        for (int i = t; i < NANCH; i += 1024) {
            u32 u = (u32)(keys[i] >> 32);
            if ((u & maskdone) == pfx) atomicAdd(&sh.h[t & 3][(u >> shift) & (nbins - 1)], 1u);
        }
        __syncthreads();
        for (int i = t; i < nbins; i += 1024)
            sh.h[0][i] = sh.h[0][i] + sh.h[1][i] + sh.h[2][i] + sh.h[3][i];
        __syncthreads();
        u32* A = sh.h[0]; u32* B = sh.h[1];
        for (int st = 1; st < nbins; st <<= 1) {
            for (int i = t; i < nbins; i += 1024)
                B[i] = A[i] + ((i + st < nbins) ? A[i + st] : 0u);
            __syncthreads();
            u32* tmp = A; A = B; B = tmp;
        }
        int rk = s_rank;
        for (int i = t; i < nbins; i += 1024) {
            u32 ge = A[i];
            u32 gt = (i + 1 < nbins) ? A[i + 1] : 0u;
            if (ge >= (u32)rk && gt < (u32)rk) { s_bin = i; s_cntgt = (int)gt; }
        }
        __syncthreads();
        if (t == 0) {
            s_prefix |= ((u32)s_bin) << shift;
            s_rank -= s_cntgt;
        }
        maskdone |= (u32)(nbins - 1) << shift;
        __syncthreads();
    }
    u32 pivot = s_prefix;
    if (t == 0) s_cnt = 0;
    __syncthreads();
    for (int i = t; i < NANCH; i += 1024) {
        u64 k = keys[i]; u32 u = (u32)(k >> 32);
        if (u > pivot) { u32 p = atomicAdd(&s_cnt, 1u); sh.sortb[p] = k; }
    }
    __syncthreads();
    for (int i = t; i < NANCH; i += 1024) {
        u64 k = keys[i]; u32 u = (u32)(k >> 32);
        if (u == pivot) { u32 p = atomicAdd(&s_cnt, 1u); if (p < 2048) sh.sortb[p] = k; }
    }
    __syncthreads();
    u32 nc = s_cnt; if (nc > 2048) nc = 2048;
    for (int i = t; i < 2048; i += 1024) if ((u32)i >= nc) sh.sortb[i] = 0ull;
    __syncthreads();
    for (int k = 2; k <= 2048; k <<= 1) {
        for (int j = k >> 1; j > 0; j >>= 1) {
            __syncthreads();
            for (int i = t; i < 2048; i += 1024) {
                int ixj = i ^ j;
                if (ixj > i) {
                    u64 a = sh.sortb[i], c = sh.sortb[ixj];
                    bool first = ((i & k) == 0);
                    if (first ? (a < c) : (a > c)) { sh.sortb[i] = c; sh.sortb[ixj] = a; }
                }
            }
        }
    }
    __syncthreads();
    for (int i = t; i < NCAND; i += 1024) {
        u64 k = sh.sortb[i];
        u32 u = (u32)(k >> 32);
        u32 fb = (u & 0x80000000u) ? (u ^ 0x80000000u) : ~u;
        float s = __uint_as_float(fb);
        int idx = (int)(0xFFFFFFFFu - (u32)k);
        size_t gi = (size_t)img * NANCH + idx;
        float4 bx = *(const float4*)&boxes_all[gi * 4];
        int cl = cls_all[gi];
        int o = img * NCAND + i;
        *(float4*)&cbox[(size_t)o * 4] = bx;
        float off = (float)cl * 4096.0f;
        float4 ob; ob.x = bx.x + off; ob.y = bx.y + off; ob.z = bx.z + off; ob.w = bx.w + off;
        *(float4*)&coff[(size_t)o * 4] = ob;
        cscore[o] = s;
        ccls[o] = cl;
    }
}

// ---------------------------------------------------------------------------
// L6: nms_mask (126 blocks) || seg combine1 (800 blocks)
// ---------------------------------------------------------------------------
__global__ __launch_bounds__(256) void nmsmask_comb1_kernel(
    const float* __restrict__ coff, u64* __restrict__ maskbuf,
    const float* __restrict__ parts, const float* __restrict__ gain,
    const float* __restrict__ bias, unsigned short* __restrict__ outb)
{
    int blk = blockIdx.x, t = threadIdx.x;
    if (blk >= 126) {
        seg_combine_body((blk - 126) * 256 + t, parts, gain, bias, outb, 4, 2*1600*256/4, 256, 0);
        return;
    }
    int img = blk / 63;
    int tid = (blk % 63) * 256 + t;
    if (tid >= NCAND * 16) return;
    int i = tid >> 4, jw = tid & 15;
    const float* cb = coff + (size_t)img * NCAND * 4;
    float ax1 = cb[i*4+0], ay1 = cb[i*4+1], ax2 = cb[i*4+2], ay2 = cb[i*4+3];
    float aarea = (ax2 - ax1) * (ay2 - ay1);
    u64 bits = 0;
    for (int jj = 0; jj < 64; jj++) {
        int j = jw * 64 + jj;
        if (j >= NCAND) break;
        float bx1 = cb[j*4+0], by1 = cb[j*4+1], bx2 = cb[j*4+2], by2 = cb[j*4+3];
        float barea = (bx2 - bx1) * (by2 - by1);
        float ltx = fmaxf(ax1, bx1), lty = fmaxf(ay1, by1);
        float rbx = fminf(ax2, bx2), rby = fminf(ay2, by2);
        float ww = fmaxf(rbx - ltx, 0.0f), hh = fmaxf(rby - lty, 0.0f);
        float inter = ww * hh;
        float iou = inter / (aarea + barea - inter + 1e-7f);
        if (iou > 0.45f) bits |= (1ull << jj);
    }
    maskbuf[((size_t)img * 1024 + i) * 16 + jw] = bits;
}

// ---------------------------------------------------------------------------
// L7: nms_serial (2 blocks) || resize_add2 (1600 blocks)
// ---------------------------------------------------------------------------
__global__ __launch_bounds__(256) void nmsserial_resize2_kernel(
    const float* __restrict__ cbox, const float* __restrict__ cscore,
    const int* __restrict__ ccls, const u64* __restrict__ maskbuf,
    float* __restrict__ out, float* __restrict__ rois,
    int* __restrict__ lab, float* __restrict__ validf,
    const unsigned short* __restrict__ f1, const unsigned short* __restrict__ x0n,
    unsigned short* __restrict__ r2b)
{
    __shared__ float sS[1024];
    int t = threadIdx.x;
    if (blockIdx.x >= 2) {
        resize_add_body(((int)blockIdx.x - 2) * 256 + t, f1, x0n, r2b, 32, 256, 40, 40, 80, 80);
        return;
    }
    int img = blockIdx.x;
    for (int i = t; i < 1024; i += 256)
        sS[i] = (i < NCAND) ? cscore[img * NCAND + i] : -1.0f;
    __syncthreads();
    if (t >= 64) return;
    int lane = t;
    u64 validw = 0;
    #pragma unroll
    for (int w = 0; w < 16; w++) {
        u64 b = __ballot(sS[w * 64 + lane] > 0.15f);
        if (lane == w) validw = b;
    }
    const u64* mrow = maskbuf + (size_t)img * 1024 * 16;
    int lw = lane & 15;
    u64 rowsel = (lane < 16) ? ~0ull : 0ull;
    u64 suppw = 0, keepw = 0;
    int kcount = 0;
    u64 ring[16];
    #pragma unroll
    for (int k = 0; k < 16; k++) ring[k] = mrow[(size_t)k * 16 + lw];
    for (int ib = 0; ib < 1024; ib += 16) {
        #pragma unroll
        for (int k = 0; k < 16; k++) {
            int i = ib + k;
            u64 row = ring[k];
            ring[k] = mrow[(size_t)((i + 16) & 1023) * 16 + lw];
            int sh = i & 63;
            bool owner_valid = (lane == (i >> 6)) && ((validw >> sh) & 1ull);
            bool mine = owner_valid && !((suppw >> sh) & 1ull);
            u64 bal = __ballot(mine);
            u64 keepall = bal ? ~0ull : 0ull;
            kcount += bal ? 1 : 0;
            suppw |= row & rowsel & keepall;
            keepw |= ((u64)mine) << sh;
        }
        if (kcount >= 100) break;
    }
    int cnt = (lane < 16) ? __popcll(keepw) : 0;
    int pre = 0, total = 0;
    for (int l = 0; l < 16; l++) {
        int c = __shfl(cnt, l);
        if (l < lane) pre += c;
        total += c;
    }
    int kc = total < 100 ? total : 100;
    if (lane < 16) {
        int r = pre;
        u64 kw = keepw;
        while (kw) {
            int b = __ffsll((long long)kw) - 1;
            kw &= kw - 1;
            if (r < 100) {
                int i = lane * 64 + b;
                int ci = img * NCAND + i;
                int slot = img * 100 + r;
                float4 bx = *(const float4*)&cbox[(size_t)ci * 4];
                *(float4*)&out[(size_t)slot * 4] = bx;
                out[800 + slot] = sS[i];
                out[1000 + slot] = (float)(ccls[ci] + 1);
                out[1200 + slot] = 1.0f;
                float4 rv; rv.x = bx.x * 0.125f; rv.y = bx.y * 0.125f; rv.z = bx.z * 0.125f; rv.w = bx.w * 0.125f;
                *(float4*)&rois[(size_t)slot * 4] = rv;
                lab[slot] = ccls[ci];
                validf[slot] = 1.0f;
            }
            r++;
        }
    }
    for (int s = kc + lane; s < 100; s += 64) {
        int slot = img * 100 + s;
        float4 z; z.x = 0; z.y = 0; z.z = 0; z.w = 0;
        *(float4*)&out[(size_t)slot * 4] = z;
        out[800 + slot] = 0.0f;
        out[1000 + slot] = 0.0f;
        out[1200 + slot] = 0.0f;
        *(float4*)&rois[(size_t)slot * 4] = z;
        lab[slot] = 0;
        validf[slot] = 0.0f;
    }
}

// ---------------------------------------------------------------------------
// Fused mask conv v7 (R18 best): 4-way oc split + XCD swizzle + hoisted ptrs.
// ---------------------------------------------------------------------------
#define SC_CHSTRIDE 18432          // 9*2048 shorts per chunk
#define SC_OCBS     73728          // ocb64 stride: 4 chunks * 18432
__global__ __launch_bounds__(256) void mfma_conv_mask(
    const unsigned short* __restrict__ in, const unsigned short* __restrict__ wp,
    const float* __restrict__ gain, const float* __restrict__ bias,
    const float* __restrict__ wml, const int* __restrict__ lab,
    const float* __restrict__ validf,
    int d0, float* __restrict__ pdot, const float* __restrict__ zerobuf)
{
    __shared__ __align__(16) char smem[XBUF];
    __shared__ float wsh[32];
    int id = blockIdx.x;
    int xcd = id & 7;
    int slot = id >> 3;
    int sub = slot & 15;
    int dgrp = slot >> 4;
    int dl = dgrp * 8 + xcd;
    int d = d0 + dl;
    if (validf[d] == 0.0f) return;
    int tile = sub >> 2, oq = sub & 3;
    int tY = tile >> 1, tX = tile & 1;
    int y0 = tY << 4, x0 = tX << 4;
    int oc0 = oq << 5;
    int ocb64 = oc0 >> 6;
    int olocal = oc0 & 63;
    int t = threadIdx.x;
    int lane = t & 63, wv = t >> 6;
    int lg = lane >> 4, lr = lane & 15;
    const unsigned short* inb = in + (size_t)dl * 784 * 128;
    const unsigned short* wpb = wp + (size_t)ocb64 * SC_OCBS;
    int spix = lane >> 2, sg = lane & 3;
    int L = lab[d];
    if (t < 32) wsh[t] = wml[(size_t)L * 128 + oc0 + t];

    const unsigned short* abase[6];
    #pragma unroll
    for (int s = 0; s < 6; s++) {
        int i = wv + s * 4;
        int pix = i * 16 + spix;
        int yy = (pix * 57) >> 10;
        int xx = pix - yy * 18;
        int gy = y0 - 1 + yy, gx = x0 - 1 + xx;
        bool oob = (i >= 21) || (pix >= 324) || (gy < 0) || (gy >= 28) || (gx < 0) || (gx >= 28);
        int gsw = sg ^ swz(pix);
        abase[s] = oob ? (const unsigned short*)zerobuf
                       : inb + (size_t)(gy * 28 + gx) * 128 + gsw * 8;
    }

    f32x4 acc[4][2];
    #pragma unroll
    for (int p = 0; p < 4; p++)
        #pragma unroll
        for (int q = 0; q < 2; q++)
            acc[p][q] = (f32x4){0.f, 0.f, 0.f, 0.f};

    for (int ch = 0; ch < 4; ch++) {
        {
            int c0 = ch << 5;
            char* dst0 = smem + wv * 1024;
            #pragma unroll
            for (int s = 0; s < 6; s++) {
                int i = wv + s * 4;
                if (i < 21) gload16(abase[s] + c0, dst0 + s * 4096);
            }
        }
        __syncthreads();
        const char* sx = smem;
        const unsigned short* wsrc = wpb + (size_t)ch * SC_CHSTRIDE;
        #pragma unroll 3
        for (int tap = 0; tap < 9; tap++) {
            int dy = tap / 3, dx = tap - dy * 3;
            bf16x8 wf[2];
            #pragma unroll
            for (int q = 0; q < 2; q++)
                wf[q] = *(const bf16x8*)(wsrc + (size_t)(tap * 64 + olocal + q * 16 + lr) * 32 + lg * 8);
            #pragma unroll
            for (int p = 0; p < 4; p++) {
                int pix = ((wv << 2) + p + dy) * 18 + dx + lr;
                bf16x8 xf = *(const bf16x8*)(sx + (pix << 6) + ((lg ^ swz(pix)) << 4));
                #pragma unroll
                for (int q = 0; q < 2; q++)
                    acc[p][q] = __builtin_amdgcn_mfma_f32_16x16x32_bf16(wf[q], xf, acc[p][q], 0, 0, 0);
            }
        }
        __syncthreads();
    }
    int x = x0 + lr;
    #pragma unroll
    for (int p = 0; p < 4; p++) {
        int y = y0 + (wv << 2) + p;
        float part = 0.0f;
        #pragma unroll
        for (int q = 0; q < 2; q++) {
            #pragma unroll
            for (int r2 = 0; r2 < 4; r2++) {
                int ol = (q << 4) + (lg << 2) + r2;
                float v = acc[p][q][r2] * gain[oc0 + ol] + bias[oc0 + ol];
                v = silu_fast(v);
                part = fmaf(wsh[ol], v, part);
            }
        }
        part += __shfl_xor(part, 16);
        part += __shfl_xor(part, 32);
        if (lg == 0 && x < 28 && y < 28)
            pdot[((size_t)oq * 200 + d) * 784 + y * 28 + x] = part;
    }
}

// ---------------------------------------------------------------------------
// mask combine: sum the four oc-quarter partial dots + bias, sigmoid, valid
// ---------------------------------------------------------------------------
__global__ void mask_combine_kernel(const float* __restrict__ pdot,
    const float* __restrict__ bml, const int* __restrict__ lab,
    const float* __restrict__ validf, float* __restrict__ out)
{
    int tid = blockIdx.x * 256 + threadIdx.x;
    if (tid >= 200 * 784) return;
    int d = tid / 784;
    if (validf[d] == 0.0f) { out[1400 + tid] = 0.0f; return; }
    const size_t S = (size_t)200 * 784;
    float s = pdot[tid] + pdot[S + tid] + pdot[2 * S + tid] + pdot[3 * S + tid] + bml[lab[d]];
    out[1400 + tid] = 1.0f / (1.0f + __expf(-s));
}

// ---------------------------------------------------------------------------
// ROI-align (28x28) + SiLU, NHWC bf16 in/out, c-inner. Early-exit invalid dets.
// ---------------------------------------------------------------------------
__global__ void roi_silu_kernel(const unsigned short* __restrict__ fseg,
    const float* __restrict__ rois, const float* __restrict__ validf,
    int d0, int total, unsigned short* __restrict__ hbuf)
{
    int tid = blockIdx.x * 256 + threadIdx.x;
    if (tid >= total) return;
    int cg = tid & 15; int r = tid >> 4;
    int p = r % 784; int dl = r / 784;
    int d = d0 + dl; int b = d / 100;
    if (validf[d] == 0.0f) return;
    int py = p / 28, px = p % 28;
    const float* ro = rois + (size_t)d * 4;
    float x1 = ro[0], y1 = ro[1], x2 = ro[2], y2 = ro[3];
    float rw = fmaxf(x2 - x1, 1.0f), rh = fmaxf(y2 - y1, 1.0f);
    float cx = x1 + (((float)px + 0.5f) / 28.0f) * rw;
    float cy = y1 + (((float)py + 0.5f) / 28.0f) * rh;
    cx = fminf(fmaxf(cx, 0.0f), 79.0f);
    cy = fminf(fmaxf(cy, 0.0f), 79.0f);
    int ix0 = (int)floorf(cx), iy0 = (int)floorf(cy);
    int ix1 = min(ix0 + 1, 79), iy1 = min(iy0 + 1, 79);
    float lx = cx - (float)ix0, ly = cy - (float)iy0;
    const unsigned short* fb = fseg + (size_t)b * 6400 * 128 + cg * 8;
    bf16x8 v00 = *(const bf16x8*)&fb[(size_t)(iy0 * 80 + ix0) * 128];
    bf16x8 v01 = *(const bf16x8*)&fb[(size_t)(iy0 * 80 + ix1) * 128];
    bf16x8 v10 = *(const bf16x8*)&fb[(size_t)(iy1 * 80 + ix0) * 128];
    bf16x8 v11 = *(const bf16x8*)&fb[(size_t)(iy1 * 80 + ix1) * 128];
    float w00 = (1.0f - ly) * (1.0f - lx), w01 = (1.0f - ly) * lx;
    float w10 = ly * (1.0f - lx), w11 = ly * lx;
    bf16x8 o;
    #pragma unroll
    for (int j = 0; j < 8; j++) {
        float v = b2f((unsigned short)v00[j]) * w00 + b2f((unsigned short)v01[j]) * w01
                + b2f((unsigned short)v10[j]) * w10 + b2f((unsigned short)v11[j]) * w11;
        o[j] = (short)f2b(silu_fast(v));
    }
    *(bf16x8*)&hbuf[((size_t)dl * 784 + p) * 128 + cg * 8] = o;
}

// ---------------------------------------------------------------------------

extern "C" void kernel_launch(void* const* d_in, const int* in_sizes, int n_in,
                              void* d_out, int out_size, void* d_ws, size_t ws_size,
                              hipStream_t stream)
{
    const float* x0 = (const float*)d_in[0];
    const float* x1 = (const float*)d_in[1];
    const float* x2 = (const float*)d_in[2];
    const float* w_det0 = (const float*)d_in[3];
    const float* b_det0 = (const float*)d_in[4];
    const float* w_det1 = (const float*)d_in[5];
    const float* b_det1 = (const float*)d_in[6];
    const float* w_det2 = (const float*)d_in[7];
    const float* b_det2 = (const float*)d_in[8];
    const float* w_seg0 = (const float*)d_in[9];
    const float* g_seg0 = (const float*)d_in[10];
    const float* b_seg0 = (const float*)d_in[11];
    const float* w_seg1 = (const float*)d_in[12];
    const float* g_seg1 = (const float*)d_in[13];
    const float* b_seg1 = (const float*)d_in[14];
    const float* w_seg2 = (const float*)d_in[15];
    const float* g_seg2 = (const float*)d_in[16];
    const float* b_seg2 = (const float*)d_in[17];
    const float* w_sc = (const float*)d_in[18];
    const float* g_sc = (const float*)d_in[19];
    const float* b_sc = (const float*)d_in[20];
    const float* w_ml = (const float*)d_in[21];
    const float* b_ml = (const float*)d_in[22];
    float* out = (float*)d_out;

    char* ws = (char*)d_ws;
    size_t off = 0;
    auto alloc = [&](size_t bytes) -> void* {
        off = (off + 255) & ~(size_t)255;
        void* p = ws + off;
        off += bytes;
        return p;
    };
    float* co0    = (float*)alloc((size_t)2 * 255 * 6400 * 4);
    float* co1    = (float*)alloc((size_t)2 * 255 * 1600 * 4);
    float* co2    = (float*)alloc((size_t)2 * 255 * 400 * 4);
    float* boxesA = (float*)alloc((size_t)2 * NANCH * 4 * 4);
    u64*   keysA  = (u64*)  alloc((size_t)2 * NANCH * 8);
    int*   clsA   = (int*)  alloc((size_t)2 * NANCH * 4);
    float* cbox   = (float*)alloc((size_t)2 * NCAND * 4 * 4);
    float* coffb  = (float*)alloc((size_t)2 * NCAND * 4 * 4);
    float* cscore = (float*)alloc((size_t)2 * NCAND * 4);
    int*   ccls   = (int*)  alloc((size_t)2 * NCAND * 4);
    u64*   maskb  = (u64*)  alloc((size_t)2 * 1024 * 16 * 8);
    // det transposed weights [C][256]
    float* wdt0   = (float*)alloc((size_t)256 * 256 * 4);
    float* wdt1   = (float*)alloc((size_t)512 * 256 * 4);
    float* wdt2   = (float*)alloc((size_t)1024 * 256 * 4);
    // NHWC bf16 inputs
    unsigned short* x0n = (unsigned short*)alloc((size_t)2 * 6400 * 256 * 2);
    unsigned short* x1n = (unsigned short*)alloc((size_t)2 * 1600 * 512 * 2);
    unsigned short* x2n = (unsigned short*)alloc((size_t)2 * 400 * 1024 * 2);
    // prepped bf16 conv weights
    const size_t s0 = (size_t)512 * 1024 * 9, s1 = (size_t)256 * 512 * 9,
                 s2 = (size_t)128 * 256 * 9,  s3 = (size_t)128 * 128 * 9;
    unsigned short* wprep = (unsigned short*)alloc((s0 + s1 + s2 + s3) * 2);
    // split-K partial buffers: det1+det2 disjoint; seg0 has its OWN buffer
    float* pbuf = (float*)alloc((size_t)4 * 2 * 1600 * 256 * 4);   // 13.1 MB
    float* pbuf2 = pbuf + (size_t)2 * 2 * 255 * 1600;              // det2 region
    float* segp0 = (float*)alloc((size_t)4 * 2 * 400 * 512 * 4);   // 6.6 MB
    // seg chain (NHWC bf16)
    unsigned short* f0   = (unsigned short*)alloc((size_t)2 * 400 * 512 * 2);
    unsigned short* r1b  = (unsigned short*)alloc((size_t)2 * 1600 * 512 * 2);
    unsigned short* f1   = (unsigned short*)alloc((size_t)2 * 1600 * 256 * 2);
    unsigned short* r2b  = (unsigned short*)alloc((size_t)2 * 6400 * 256 * 2);
    unsigned short* fseg = (unsigned short*)alloc((size_t)2 * 6400 * 128 * 2);
    float* zerobuf = (float*)alloc(2048);
    float* roisW  = (float*)alloc((size_t)200 * 4 * 4);
    int*   labW   = (int*)  alloc((size_t)200 * 4);
    float* validW = (float*)alloc((size_t)200 * 4);
    float* pdot   = (float*)alloc((size_t)4 * 200 * 784 * 4);   // 2.5 MB
    unsigned short* hbuf   = (unsigned short*)alloc((size_t)200 * 784 * 128 * 2);

    int DCH = 200;
    if (off > ws_size) {
        DCH = 25;
        hbuf = (unsigned short*)co0;
    }

    // --- 1. merged prep ---
    prep_all_kernel<<<4289, 256, 0, stream>>>(
        w_det0, w_det1, w_det2, wdt0, wdt1, wdt2,
        w_seg0, w_seg1, w_seg2, w_sc,
        wprep, wprep + s0, wprep + s0 + s1, wprep + s0 + s1 + s2,
        x0, x1, x2, x0n, x1n, x2n, zerobuf);

    // --- 2. seg0 conv (FIRST: generation-1 residency) || det convs ---
    detseg_conv_kernel<<<2048, 256, 0, stream>>>(
        x0, wdt0, b_det0, co0,
        x1, wdt1, b_det1, pbuf,
        x2, wdt2, b_det2, pbuf2,
        x2n, wprep, g_seg0, b_seg0, f0, zerobuf, segp0);

    // --- 3. det combines || seg combine0 ---
    combine_both_kernel<<<1397, 256, 0, stream>>>(pbuf, b_det1, co1, pbuf2, b_det2, co2,
                                                  segp0, g_seg0, b_seg0, f0);

    // --- 4. decode || resize_add1 ---
    decode_resize1_kernel<<<998, 256, 0, stream>>>(co0, co1, co2, boxesA, keysA, clsA,
                                                   f0, x1n, r1b);

    // --- 5. topk || seg1 conv ---
    topk_seg1_kernel<<<290, 1024, 0, stream>>>(keysA, boxesA, clsA,
        cbox, coffb, cscore, ccls,
        r1b, wprep + s0, g_seg1, b_seg1, f1, zerobuf, pbuf);

    // --- 6. nms_mask || seg combine1 ---
    nmsmask_comb1_kernel<<<926, 256, 0, stream>>>(coffb, maskb,
        pbuf, g_seg1, b_seg1, f1);

    // --- 7. nms_serial || resize_add2 ---
    nmsserial_resize2_kernel<<<1602, 256, 0, stream>>>(cbox, cscore, ccls, maskb,
        out, roisW, labW, validW, f1, x0n, r2b);

    // --- 8-9. seg2 conv + combine2 ---
    mfma_conv3x3<<<208, 256, 0, stream>>>(r2b, wprep + s0 + s1, g_seg2, b_seg2, fseg, zerobuf, 256, 128, 80, 80, 0, 2, pbuf);
    seg_combine_kernel<<<1600, 256, 0, stream>>>(pbuf, g_seg2, b_seg2, fseg, 2, 2*6400*128/4, 128, 0);

    // --- 10-12. mask branch ---
    for (int d0i = 0; d0i < 200; d0i += DCH) {
        int total = DCH * 784 * 16;
        roi_silu_kernel<<<(total + 255) / 256, 256, 0, stream>>>(fseg, roisW, validW, d0i, total, hbuf);
        mfma_conv_mask<<<DCH * 16, 256, 0, stream>>>(hbuf, wprep + s0 + s1 + s2,
            g_sc, b_sc, w_ml, labW, validW, d0i, pdot, zerobuf);
    }
    mask_combine_kernel<<<(200 * 784 + 255) / 256, 256, 0, stream>>>(pdot, b_ml, labW, validW, out);
}